// Round 2
// baseline (1329.997 us; speedup 1.0000x reference)
//
#include <hip/hip_runtime.h>
#include <hip/hip_bf16.h>

#define N_NODES 100000
#define N_EDGES 3200000
#define NGRAPH 1024
#define KTOP 30
#define NB_SCAN ((N_NODES + 255) / 256)   // 391

typedef __hip_bfloat16 bf16;

// Flag-steered load of a "float tensor" input that may be bf16 or f32 on device.
__device__ __forceinline__ float LD(const void* p, int i, int bf) {
    if (bf) {
        unsigned short h = ((const unsigned short*)p)[i];
        return __uint_as_float(((unsigned int)h) << 16);
    }
    return ((const float*)p)[i];
}

// ---------- dtype probe: decide bf16 vs f32 from w1's bit patterns ----------
__global__ void k_detect(const void* w1, int* flag) {
    if (threadIdx.x == 0 && blockIdx.x == 0) {
        const unsigned short* u = (const unsigned short*)w1;
        int plausible = 0;
        for (int i = 0; i < 64; i++) {
            unsigned short h = u[2 * i];              // even bf16 slots
            float v = __uint_as_float(((unsigned int)h) << 16);
            float a = fabsf(v);
            if (a == 0.f || (a >= 9.765625e-4f && a <= 2.0f)) plausible++;
        }
        // bf16 data: ~63/64 plausible. f32 mantissa junk: ~3/64.
        *flag = (plausible >= 40) ? 1 : 0;
    }
}

// ---------- graph preprocessing ----------
__global__ void k_edge_count(const int* __restrict__ src, const int* __restrict__ dst,
                             int* __restrict__ cnt) {
    int e = blockIdx.x * 256 + threadIdx.x;
    if (e >= N_EDGES) return;
    int s = src[e], d = dst[e];
    if (s != d) atomicAdd(&cnt[d], 1);
}

__global__ void k_gcount(const int* __restrict__ batch, int* __restrict__ gcnt) {
    int i = blockIdx.x * 256 + threadIdx.x;
    if (i >= N_NODES) return;
    atomicAdd(&gcnt[batch[i]], 1);
}

__global__ void k_dis(const int* __restrict__ cnt, float* __restrict__ dis) {
    int i = blockIdx.x * 256 + threadIdx.x;
    if (i >= N_NODES) return;
    dis[i] = rsqrtf((float)cnt[i] + 1.0f);
}

__global__ void k_scan1(const int* __restrict__ cnt, int* __restrict__ ex,
                        int* __restrict__ bsum) {
    __shared__ int sh[256];
    int i = blockIdx.x * 256 + threadIdx.x;
    int v = (i < N_NODES) ? cnt[i] : 0;
    sh[threadIdx.x] = v;
    __syncthreads();
    for (int off = 1; off < 256; off <<= 1) {
        int t = (threadIdx.x >= off) ? sh[threadIdx.x - off] : 0;
        __syncthreads();
        sh[threadIdx.x] += t;
        __syncthreads();
    }
    if (i < N_NODES) ex[i] = sh[threadIdx.x] - v;
    if (threadIdx.x == 255) bsum[blockIdx.x] = sh[255];
}

__global__ void k_scan2(const int* __restrict__ bsum, int* __restrict__ bex, int nb) {
    __shared__ int sh[512];
    int v = ((int)threadIdx.x < nb) ? bsum[threadIdx.x] : 0;
    sh[threadIdx.x] = v;
    __syncthreads();
    for (int off = 1; off < 512; off <<= 1) {
        int t = (threadIdx.x >= off) ? sh[threadIdx.x - off] : 0;
        __syncthreads();
        sh[threadIdx.x] += t;
        __syncthreads();
    }
    bex[threadIdx.x] = sh[threadIdx.x] - v;  // bex[b] == total for b >= nb
}

__global__ void k_scan3(int* __restrict__ ex, const int* __restrict__ bex,
                        int* __restrict__ cursor) {
    int i = blockIdx.x * 256 + threadIdx.x;
    if (i > N_NODES) return;
    if (i == N_NODES) { ex[N_NODES] = bex[NB_SCAN]; return; }
    int r = ex[i] + bex[i >> 8];
    ex[i] = r;
    cursor[i] = r;
}

__global__ void k_gscan(const int* __restrict__ gcnt, int* __restrict__ gstart) {
    __shared__ int sh[NGRAPH];
    int v = gcnt[threadIdx.x];
    sh[threadIdx.x] = v;
    __syncthreads();
    for (int off = 1; off < NGRAPH; off <<= 1) {
        int t = (threadIdx.x >= off) ? sh[threadIdx.x - off] : 0;
        __syncthreads();
        sh[threadIdx.x] += t;
        __syncthreads();
    }
    gstart[threadIdx.x] = sh[threadIdx.x] - v;
    if (threadIdx.x == NGRAPH - 1) gstart[NGRAPH] = sh[NGRAPH - 1];
}

__global__ void k_fill(const int* __restrict__ src, const int* __restrict__ dst,
                       int* __restrict__ cursor, int* __restrict__ csr) {
    int e = blockIdx.x * 256 + threadIdx.x;
    if (e >= N_EDGES) return;
    int s = src[e], d = dst[e];
    if (s != d) {
        int p = atomicAdd(&cursor[d], 1);
        csr[p] = s;
    }
}

// ---------- GCN layers (internal activations always f32) ----------
__global__ __launch_bounds__(256) void k_mm1(const void* __restrict__ x,
                                             const void* __restrict__ w,
                                             const int* __restrict__ flagp,
                                             float* __restrict__ t) {
    __shared__ float Wl[128 * 32];
    __shared__ float Xs[8 * 128];
    int bf = *flagp;
    for (int idx = threadIdx.x; idx < 128 * 32; idx += 256) Wl[idx] = LD(w, idx, bf);
    int nbase = blockIdx.x * 8;
    for (int idx = threadIdx.x; idx < 8 * 128; idx += 256) {
        int node = nbase + (idx >> 7);
        Xs[idx] = (node < N_NODES) ? LD(x, node * 128 + (idx & 127), bf) : 0.f;
    }
    __syncthreads();
    int sub = threadIdx.x >> 5, col = threadIdx.x & 31;
    int node = nbase + sub;
    if (node >= N_NODES) return;
    float acc = 0.f;
    const float* xr = &Xs[sub * 128];
#pragma unroll 8
    for (int k = 0; k < 128; k++) acc += xr[k] * Wl[k * 32 + col];
    t[node * 32 + col] = acc;
}

__global__ __launch_bounds__(256) void k_mm32(const float* __restrict__ xin,
                                              const void* __restrict__ w,
                                              const int* __restrict__ flagp,
                                              float* __restrict__ t) {
    __shared__ float Wl[32 * 32];
    __shared__ float Xs[8 * 32];
    int bf = *flagp;
    for (int idx = threadIdx.x; idx < 1024; idx += 256) Wl[idx] = LD(w, idx, bf);
    int nbase = blockIdx.x * 8;
    {
        int node = nbase + (threadIdx.x >> 5);
        Xs[threadIdx.x] = (node < N_NODES) ? xin[node * 32 + (threadIdx.x & 31)] : 0.f;
    }
    __syncthreads();
    int sub = threadIdx.x >> 5, col = threadIdx.x & 31;
    int node = nbase + sub;
    if (node >= N_NODES) return;
    float acc = 0.f;
    const float* xr = &Xs[sub * 32];
#pragma unroll
    for (int k = 0; k < 32; k++) acc += xr[k] * Wl[k * 32 + col];
    t[node * 32 + col] = acc;
}

__global__ __launch_bounds__(256) void k_mm_out1(const float* __restrict__ xin,
                                                 const void* __restrict__ w4,
                                                 const int* __restrict__ flagp,
                                                 float* __restrict__ t4) {
    int node = blockIdx.x * 256 + threadIdx.x;
    if (node >= N_NODES) return;
    int bf = *flagp;
    float acc = 0.f;
#pragma unroll
    for (int k = 0; k < 32; k++) acc += xin[node * 32 + k] * LD(w4, k, bf);
    t4[node] = acc;
}

__global__ __launch_bounds__(256) void k_agg32(const float* __restrict__ t,
                                               const int* __restrict__ rs,
                                               const int* __restrict__ csr,
                                               const float* __restrict__ dis,
                                               const void* __restrict__ b,
                                               const int* __restrict__ flagp,
                                               float* __restrict__ out) {
    int node = blockIdx.x * 8 + (threadIdx.x >> 5);
    int lane = threadIdx.x & 31;
    if (node >= N_NODES) return;
    int bf = *flagp;
    int s = rs[node], e = rs[node + 1];
    float acc = 0.f;
    for (int i = s; i < e; i++) {
        int v = csr[i];
        acc += dis[v] * t[v * 32 + lane];
    }
    float d = dis[node];
    float r = d * acc + t[node * 32 + lane] * (d * d) + LD(b, lane, bf);
    out[node * 32 + lane] = tanhf(r);
}

__global__ __launch_bounds__(256) void k_agg1(const float* __restrict__ t4,
                                              const int* __restrict__ rs,
                                              const int* __restrict__ csr,
                                              const float* __restrict__ dis,
                                              const void* __restrict__ b4,
                                              const int* __restrict__ flagp,
                                              float* __restrict__ x4) {
    int node = blockIdx.x * 256 + threadIdx.x;
    if (node >= N_NODES) return;
    int bf = *flagp;
    int s = rs[node], e = rs[node + 1];
    float acc = 0.f;
    for (int i = s; i < e; i++) {
        int v = csr[i];
        acc += dis[v] * t4[v];
    }
    float d = dis[node];
    x4[node] = tanhf(d * acc + t4[node] * (d * d) + LD(b4, 0, bf));
}

// ---------- SortPooling rank ----------
__global__ __launch_bounds__(256) void k_rank(const int* __restrict__ batch,
                                              const int* __restrict__ gstart,
                                              const float* __restrict__ x4,
                                              int* __restrict__ sel) {
    int i = blockIdx.x * 256 + threadIdx.x;
    if (i >= N_NODES) return;
    int g = batch[i];
    int s = gstart[g], e = gstart[g + 1];
    float ki = x4[i];
    int rank = 0;
    for (int j = s; j < e; j++) {
        float kj = x4[j];
        rank += (kj > ki) || (kj == ki && j < i);
    }
    if (rank < KTOP) sel[g * KTOP + rank] = i;
}

// ---------- CNN/MLP head: one block (128 threads) per graph ----------
__global__ __launch_bounds__(128) void k_head(
    const float* __restrict__ x1, const float* __restrict__ x2,
    const float* __restrict__ x3, const float* __restrict__ x4,
    const int* __restrict__ sel, const void* __restrict__ w5, const void* __restrict__ b5,
    const void* __restrict__ w6, const void* __restrict__ b6,
    const void* __restrict__ f1w, const void* __restrict__ f1b,
    const void* __restrict__ f2w, const void* __restrict__ f2b,
    const int* __restrict__ flagp, void* __restrict__ out) {
    __shared__ float P[KTOP][97];
    __shared__ float H5[16][30];
    __shared__ float M[16][15];
    __shared__ float H6[352];
    __shared__ float R1[128];
    __shared__ float L[10];
    __shared__ float mls;
    int g = blockIdx.x;
    int tid = threadIdx.x;
    int bf = *flagp;

    for (int idx = tid; idx < KTOP * 97; idx += 128) {
        int p = idx / 97, f = idx - p * 97;
        int v = sel[g * KTOP + p];
        float val = 0.f;
        if (v >= 0) {
            if (f < 32)      val = x1[v * 32 + f];
            else if (f < 64) val = x2[v * 32 + f - 32];
            else if (f < 96) val = x3[v * 32 + f - 64];
            else             val = x4[v];
        }
        P[p][f] = val;
    }
    __syncthreads();
    for (int idx = tid; idx < 480; idx += 128) {   // conv5 + relu
        int o = idx / 30, p = idx - o * 30;
        float acc = LD(b5, o, bf);
        for (int f = 0; f < 97; f++) acc += LD(w5, o * 97 + f, bf) * P[p][f];
        H5[o][p] = fmaxf(acc, 0.f);
    }
    __syncthreads();
    for (int idx = tid; idx < 240; idx += 128) {   // maxpool2
        int o = idx / 15, q = idx - o * 15;
        M[o][q] = fmaxf(H5[o][2 * q], H5[o][2 * q + 1]);
    }
    __syncthreads();
    for (int idx = tid; idx < 352; idx += 128) {   // conv6 + relu
        int oc = idx / 11, tp = idx - oc * 11;
        float acc = LD(b6, oc, bf);
        for (int ic = 0; ic < 16; ic++) {
#pragma unroll
            for (int k = 0; k < 5; k++)
                acc += LD(w6, (oc * 16 + ic) * 5 + k, bf) * M[ic][tp + k];
        }
        H6[idx] = fmaxf(acc, 0.f);
    }
    __syncthreads();
    {   // fc1 + relu
        float acc = LD(f1b, tid, bf);
        for (int i = 0; i < 352; i++) acc += H6[i] * LD(f1w, i * 128 + tid, bf);
        R1[tid] = fmaxf(acc, 0.f);
    }
    __syncthreads();
    if (tid < 10) {   // fc2
        float acc = LD(f2b, tid, bf);
        for (int k = 0; k < 128; k++) acc += R1[k] * LD(f2w, k * 10 + tid, bf);
        L[tid] = acc;
    }
    __syncthreads();
    if (tid == 0) {
        float m = L[0];
        for (int c = 1; c < 10; c++) m = fmaxf(m, L[c]);
        float ssum = 0.f;
        for (int c = 0; c < 10; c++) ssum += expf(L[c] - m);
        mls = m + logf(ssum);
    }
    __syncthreads();
    if (tid < 10) {
        float v = L[tid] - mls;
        if (bf) ((bf16*)out)[g * 10 + tid] = __float2bfloat16(v);
        else    ((float*)out)[g * 10 + tid] = v;
    }
}

extern "C" void kernel_launch(void* const* d_in, const int* in_sizes, int n_in,
                              void* d_out, int out_size, void* d_ws, size_t ws_size,
                              hipStream_t stream) {
    const void* x   = d_in[0];
    const void* w1  = d_in[1];  const void* b1  = d_in[2];
    const void* w2  = d_in[3];  const void* b2  = d_in[4];
    const void* w3  = d_in[5];  const void* b3  = d_in[6];
    const void* w4  = d_in[7];  const void* b4  = d_in[8];
    const void* w5  = d_in[9];  const void* b5  = d_in[10];
    const void* w6  = d_in[11]; const void* b6  = d_in[12];
    const void* f1w = d_in[13]; const void* f1b = d_in[14];
    const void* f2w = d_in[15]; const void* f2b = d_in[16];
    const int* esrc  = (const int*)d_in[17];
    const int* edst  = (const int*)d_in[18];
    const int* batch = (const int*)d_in[19];

    char* w = (char*)d_ws;
    size_t off = 0;
    auto alloc = [&](size_t bytes) {
        void* p = w + off;
        off += (bytes + 255) & ~(size_t)255;
        return p;
    };
    int*   flag   = (int*)  alloc(256);
    int*   deg    = (int*)  alloc((size_t)N_NODES * 4);        // reused as cursor
    int*   rs     = (int*)  alloc((size_t)(N_NODES + 1) * 4);
    float* dis    = (float*)alloc((size_t)N_NODES * 4);
    int*   csr    = (int*)  alloc((size_t)N_EDGES * 4);
    float* t      = (float*)alloc((size_t)N_NODES * 32 * 4);   // pre-agg buffer (also t4)
    float* x1     = (float*)alloc((size_t)N_NODES * 32 * 4);
    float* x2     = (float*)alloc((size_t)N_NODES * 32 * 4);
    float* x3     = (float*)alloc((size_t)N_NODES * 32 * 4);
    float* x4     = (float*)alloc((size_t)N_NODES * 4);
    int*   gcnt   = (int*)  alloc((size_t)NGRAPH * 4);
    int*   gstart = (int*)  alloc((size_t)(NGRAPH + 1) * 4);
    int*   sel    = (int*)  alloc((size_t)NGRAPH * KTOP * 4);
    int*   bsum   = (int*)  alloc(512 * 4);
    int*   bex    = (int*)  alloc(513 * 4);
    (void)ws_size; (void)n_in; (void)in_sizes; (void)out_size;

    hipMemsetAsync(deg, 0, (size_t)N_NODES * 4, stream);
    hipMemsetAsync(gcnt, 0, (size_t)NGRAPH * 4, stream);
    hipMemsetAsync(sel, 0xFF, (size_t)NGRAPH * KTOP * 4, stream);

    int eb = (N_EDGES + 255) / 256;
    int nb = NB_SCAN;
    int mb = (N_NODES + 7) / 8;

    k_detect<<<1, 64, 0, stream>>>(w1, flag);
    k_edge_count<<<eb, 256, 0, stream>>>(esrc, edst, deg);
    k_gcount<<<nb, 256, 0, stream>>>(batch, gcnt);
    k_dis<<<nb, 256, 0, stream>>>(deg, dis);
    k_scan1<<<nb, 256, 0, stream>>>(deg, rs, bsum);
    k_scan2<<<1, 512, 0, stream>>>(bsum, bex, nb);
    k_scan3<<<nb, 256, 0, stream>>>(rs, bex, deg);
    k_gscan<<<1, NGRAPH, 0, stream>>>(gcnt, gstart);
    k_fill<<<eb, 256, 0, stream>>>(esrc, edst, deg, csr);

    k_mm1<<<mb, 256, 0, stream>>>(x, w1, flag, t);
    k_agg32<<<mb, 256, 0, stream>>>(t, rs, csr, dis, b1, flag, x1);
    k_mm32<<<mb, 256, 0, stream>>>(x1, w2, flag, t);
    k_agg32<<<mb, 256, 0, stream>>>(t, rs, csr, dis, b2, flag, x2);
    k_mm32<<<mb, 256, 0, stream>>>(x2, w3, flag, t);
    k_agg32<<<mb, 256, 0, stream>>>(t, rs, csr, dis, b3, flag, x3);
    k_mm_out1<<<nb, 256, 0, stream>>>(x3, w4, flag, t);
    k_agg1<<<nb, 256, 0, stream>>>(t, rs, csr, dis, b4, flag, x4);
    k_rank<<<nb, 256, 0, stream>>>(batch, gstart, x4, sel);
    k_head<<<NGRAPH, 128, 0, stream>>>(x1, x2, x3, x4, sel, w5, b5, w6, b6,
                                       f1w, f1b, f2w, f2b, flag, (void*)d_out);
}

// Round 3
// 1048.109 us; speedup vs baseline: 1.2689x; 1.2689x over previous
//
#include <hip/hip_runtime.h>
#include <hip/hip_bf16.h>

#define N_NODES 100000
#define N_EDGES 3200000
#define NGRAPH 1024
#define KTOP 30
#define NB_SCAN ((N_NODES + 255) / 256)   // 391

typedef __hip_bfloat16 bf16;

// Flag-steered load of a "float tensor" input that may be bf16 or f32 on device.
__device__ __forceinline__ float LD(const void* p, int i, int bf) {
    if (bf) {
        unsigned short h = ((const unsigned short*)p)[i];
        return __uint_as_float(((unsigned int)h) << 16);
    }
    return ((const float*)p)[i];
}

// ---------- dtype probe ----------
__global__ void k_detect(const void* w1, int* flag) {
    if (threadIdx.x == 0 && blockIdx.x == 0) {
        const unsigned short* u = (const unsigned short*)w1;
        int plausible = 0;
        for (int i = 0; i < 64; i++) {
            unsigned short h = u[2 * i];
            float v = __uint_as_float(((unsigned int)h) << 16);
            float a = fabsf(v);
            if (a == 0.f || (a >= 9.765625e-4f && a <= 2.0f)) plausible++;
        }
        *flag = (plausible >= 40) ? 1 : 0;
    }
}

// ---------- graph preprocessing ----------
// Pass A: count in-degree AND record each edge's slot within its dst bucket.
__global__ void k_count_rank(const int* __restrict__ src, const int* __restrict__ dst,
                             int* __restrict__ deg, int* __restrict__ rank) {
    int e = blockIdx.x * 256 + threadIdx.x;
    if (e >= N_EDGES) return;
    int s = src[e], d = dst[e];
    int r = -1;
    if (s != d) r = atomicAdd(&deg[d], 1);
    rank[e] = r;
}

__global__ void k_scan1(const int* __restrict__ cnt, int* __restrict__ ex,
                        int* __restrict__ bsum) {
    __shared__ int sh[256];
    int i = blockIdx.x * 256 + threadIdx.x;
    int v = (i < N_NODES) ? cnt[i] : 0;
    sh[threadIdx.x] = v;
    __syncthreads();
    for (int off = 1; off < 256; off <<= 1) {
        int t = (threadIdx.x >= off) ? sh[threadIdx.x - off] : 0;
        __syncthreads();
        sh[threadIdx.x] += t;
        __syncthreads();
    }
    if (i < N_NODES) ex[i] = sh[threadIdx.x] - v;
    if (threadIdx.x == 255) bsum[blockIdx.x] = sh[255];
}

__global__ void k_scan2(const int* __restrict__ bsum, int* __restrict__ bex, int nb) {
    __shared__ int sh[512];
    int v = ((int)threadIdx.x < nb) ? bsum[threadIdx.x] : 0;
    sh[threadIdx.x] = v;
    __syncthreads();
    for (int off = 1; off < 512; off <<= 1) {
        int t = (threadIdx.x >= off) ? sh[threadIdx.x - off] : 0;
        __syncthreads();
        sh[threadIdx.x] += t;
        __syncthreads();
    }
    bex[threadIdx.x] = sh[threadIdx.x] - v;
}

// Finalize row starts; also compute dis = rsqrt(deg+1) here.
__global__ void k_scan3(int* __restrict__ ex, const int* __restrict__ bex,
                        const int* __restrict__ deg, float* __restrict__ dis) {
    int i = blockIdx.x * 256 + threadIdx.x;
    if (i > N_NODES) return;
    if (i == N_NODES) { ex[N_NODES] = bex[NB_SCAN]; return; }
    ex[i] = ex[i] + bex[i >> 8];
    dis[i] = rsqrtf((float)deg[i] + 1.0f);
}

// gstart via binary search on the (sorted) batch array.
__global__ void k_gstart(const int* __restrict__ batch, int* __restrict__ gstart) {
    int g = blockIdx.x * 256 + threadIdx.x;
    if (g > NGRAPH) return;
    int lo = 0, hi = N_NODES;
    while (lo < hi) {
        int mid = (lo + hi) >> 1;
        if (batch[mid] < g) lo = mid + 1; else hi = mid;
    }
    gstart[g] = lo;
}

// Pass B: pure scatter, no atomics.
__global__ void k_fill(const int* __restrict__ src, const int* __restrict__ dst,
                       const int* __restrict__ rank, const int* __restrict__ rs,
                       int* __restrict__ csr) {
    int e = blockIdx.x * 256 + threadIdx.x;
    if (e >= N_EDGES) return;
    int r = rank[e];
    if (r >= 0) csr[rs[dst[e]] + r] = src[e];
}

// ---------- GCN layers (activations f32; ts = dis * (x @ W)) ----------
__global__ __launch_bounds__(256) void k_mm1(const void* __restrict__ x,
                                             const void* __restrict__ w,
                                             const int* __restrict__ flagp,
                                             const float* __restrict__ dis,
                                             float* __restrict__ ts) {
    __shared__ float Wl[128 * 32];
    __shared__ float Xs[32][128];
    int bf = *flagp;
    int tid = threadIdx.x;
    for (int idx = tid; idx < 128 * 32; idx += 256) Wl[idx] = LD(w, idx, bf);
    int nbase = blockIdx.x * 32;
    for (int idx = tid; idx < 32 * 128; idx += 256) {
        int node = nbase + (idx >> 7);
        Xs[idx >> 7][idx & 127] = (node < N_NODES) ? LD(x, node * 128 + (idx & 127), bf) : 0.f;
    }
    __syncthreads();
    int grp = tid >> 5, col = tid & 31;
    for (int rep = 0; rep < 4; rep++) {
        int sub = grp + 8 * rep;
        int node = nbase + sub;
        if (node >= N_NODES) continue;
        float acc = 0.f;
#pragma unroll 8
        for (int k = 0; k < 128; k++) acc += Xs[sub][k] * Wl[k * 32 + col];
        ts[node * 32 + col] = dis[node] * acc;
    }
}

__global__ __launch_bounds__(256) void k_mm32(const float* __restrict__ xin,
                                              const void* __restrict__ w,
                                              const int* __restrict__ flagp,
                                              const float* __restrict__ dis,
                                              float* __restrict__ ts) {
    __shared__ float Wl[32 * 32];
    __shared__ float Xs[32][32];
    int bf = *flagp;
    int tid = threadIdx.x;
    for (int idx = tid; idx < 1024; idx += 256) Wl[idx] = LD(w, idx, bf);
    int nbase = blockIdx.x * 32;
    for (int idx = tid; idx < 1024; idx += 256) {
        int node = nbase + (idx >> 5);
        Xs[idx >> 5][idx & 31] = (node < N_NODES) ? xin[node * 32 + (idx & 31)] : 0.f;
    }
    __syncthreads();
    int grp = tid >> 5, col = tid & 31;
    for (int rep = 0; rep < 4; rep++) {
        int sub = grp + 8 * rep;
        int node = nbase + sub;
        if (node >= N_NODES) continue;
        float acc = 0.f;
#pragma unroll
        for (int k = 0; k < 32; k++) acc += Xs[sub][k] * Wl[k * 32 + col];
        ts[node * 32 + col] = dis[node] * acc;
    }
}

__global__ __launch_bounds__(256) void k_mm_out1(const float* __restrict__ xin,
                                                 const void* __restrict__ w4,
                                                 const int* __restrict__ flagp,
                                                 const float* __restrict__ dis,
                                                 float* __restrict__ ts4) {
    int node = blockIdx.x * 8 + (threadIdx.x >> 5);
    int lane = threadIdx.x & 31;
    if (node >= N_NODES) return;
    int bf = *flagp;
    float v = xin[node * 32 + lane] * LD(w4, lane, bf);
    for (int off = 16; off; off >>= 1) v += __shfl_down(v, off, 32);
    if (lane == 0) ts4[node] = dis[node] * v;
}

// One wave64 per node; halves take even/odd neighbors; self term folded in.
__global__ __launch_bounds__(256) void k_agg32(const float* __restrict__ ts,
                                               const int* __restrict__ rs,
                                               const int* __restrict__ csr,
                                               const float* __restrict__ dis,
                                               const void* __restrict__ b,
                                               const int* __restrict__ flagp,
                                               float* __restrict__ out) {
    int node = blockIdx.x * 4 + (threadIdx.x >> 6);
    int lane = threadIdx.x & 63;
    int feat = lane & 31;
    int half = lane >> 5;
    if (node >= N_NODES) return;
    int bf = *flagp;
    int s = rs[node], e = rs[node + 1];
    float acc = (half == 0) ? ts[node * 32 + feat] : 0.f;
    for (int i = s + half; i < e; i += 2) {
        int v = csr[i];
        acc += ts[v * 32 + feat];
    }
    acc += __shfl_down(acc, 32);
    if (half == 0) {
        float r = dis[node] * acc + LD(b, feat, bf);
        out[node * 32 + feat] = tanhf(r);
    }
}

__global__ __launch_bounds__(256) void k_agg1(const float* __restrict__ ts4,
                                              const int* __restrict__ rs,
                                              const int* __restrict__ csr,
                                              const float* __restrict__ dis,
                                              const void* __restrict__ b4,
                                              const int* __restrict__ flagp,
                                              float* __restrict__ x4) {
    int node = blockIdx.x * 256 + threadIdx.x;
    if (node >= N_NODES) return;
    int bf = *flagp;
    int s = rs[node], e = rs[node + 1];
    float acc = ts4[node];
    for (int i = s; i < e; i++) acc += ts4[csr[i]];
    x4[node] = tanhf(dis[node] * acc + LD(b4, 0, bf));
}

// ---------- SortPooling rank ----------
__global__ __launch_bounds__(256) void k_rank(const int* __restrict__ batch,
                                              const int* __restrict__ gstart,
                                              const float* __restrict__ x4,
                                              int* __restrict__ sel) {
    int i = blockIdx.x * 256 + threadIdx.x;
    if (i >= N_NODES) return;
    int g = batch[i];
    int s = gstart[g], e = gstart[g + 1];
    float ki = x4[i];
    int rank = 0;
    for (int j = s; j < e; j++) {
        float kj = x4[j];
        rank += (kj > ki) || (kj == ki && j < i);
    }
    if (rank < KTOP) sel[g * KTOP + rank] = i;
}

// ---------- CNN/MLP head ----------
__global__ __launch_bounds__(128) void k_head(
    const float* __restrict__ x1, const float* __restrict__ x2,
    const float* __restrict__ x3, const float* __restrict__ x4,
    const int* __restrict__ sel, const void* __restrict__ w5, const void* __restrict__ b5,
    const void* __restrict__ w6, const void* __restrict__ b6,
    const void* __restrict__ f1w, const void* __restrict__ f1b,
    const void* __restrict__ f2w, const void* __restrict__ f2b,
    const int* __restrict__ flagp, void* __restrict__ out) {
    __shared__ float P[KTOP][97];
    __shared__ float H5[16][30];
    __shared__ float M[16][15];
    __shared__ float H6[352];
    __shared__ float R1[128];
    __shared__ float L[10];
    __shared__ float mls;
    int g = blockIdx.x;
    int tid = threadIdx.x;
    int bf = *flagp;

    for (int idx = tid; idx < KTOP * 97; idx += 128) {
        int p = idx / 97, f = idx - p * 97;
        int v = sel[g * KTOP + p];
        float val = 0.f;
        if (v >= 0) {
            if (f < 32)      val = x1[v * 32 + f];
            else if (f < 64) val = x2[v * 32 + f - 32];
            else if (f < 96) val = x3[v * 32 + f - 64];
            else             val = x4[v];
        }
        P[p][f] = val;
    }
    __syncthreads();
    for (int idx = tid; idx < 480; idx += 128) {   // conv5 + relu
        int o = idx / 30, p = idx - o * 30;
        float acc = LD(b5, o, bf);
        for (int f = 0; f < 97; f++) acc += LD(w5, o * 97 + f, bf) * P[p][f];
        H5[o][p] = fmaxf(acc, 0.f);
    }
    __syncthreads();
    for (int idx = tid; idx < 240; idx += 128) {   // maxpool2
        int o = idx / 15, q = idx - o * 15;
        M[o][q] = fmaxf(H5[o][2 * q], H5[o][2 * q + 1]);
    }
    __syncthreads();
    for (int idx = tid; idx < 352; idx += 128) {   // conv6 + relu
        int oc = idx / 11, tp = idx - oc * 11;
        float acc = LD(b6, oc, bf);
        for (int ic = 0; ic < 16; ic++) {
#pragma unroll
            for (int k = 0; k < 5; k++)
                acc += LD(w6, (oc * 16 + ic) * 5 + k, bf) * M[ic][tp + k];
        }
        H6[idx] = fmaxf(acc, 0.f);
    }
    __syncthreads();
    {   // fc1 + relu
        float acc = LD(f1b, tid, bf);
        for (int i = 0; i < 352; i++) acc += H6[i] * LD(f1w, i * 128 + tid, bf);
        R1[tid] = fmaxf(acc, 0.f);
    }
    __syncthreads();
    if (tid < 10) {   // fc2
        float acc = LD(f2b, tid, bf);
        for (int k = 0; k < 128; k++) acc += R1[k] * LD(f2w, k * 10 + tid, bf);
        L[tid] = acc;
    }
    __syncthreads();
    if (tid == 0) {
        float m = L[0];
        for (int c = 1; c < 10; c++) m = fmaxf(m, L[c]);
        float ssum = 0.f;
        for (int c = 0; c < 10; c++) ssum += expf(L[c] - m);
        mls = m + logf(ssum);
    }
    __syncthreads();
    if (tid < 10) {
        float v = L[tid] - mls;
        if (bf) ((bf16*)out)[g * 10 + tid] = __float2bfloat16(v);
        else    ((float*)out)[g * 10 + tid] = v;
    }
}

extern "C" void kernel_launch(void* const* d_in, const int* in_sizes, int n_in,
                              void* d_out, int out_size, void* d_ws, size_t ws_size,
                              hipStream_t stream) {
    const void* x   = d_in[0];
    const void* w1  = d_in[1];  const void* b1  = d_in[2];
    const void* w2  = d_in[3];  const void* b2  = d_in[4];
    const void* w3  = d_in[5];  const void* b3  = d_in[6];
    const void* w4  = d_in[7];  const void* b4  = d_in[8];
    const void* w5  = d_in[9];  const void* b5  = d_in[10];
    const void* w6  = d_in[11]; const void* b6  = d_in[12];
    const void* f1w = d_in[13]; const void* f1b = d_in[14];
    const void* f2w = d_in[15]; const void* f2b = d_in[16];
    const int* esrc  = (const int*)d_in[17];
    const int* edst  = (const int*)d_in[18];
    const int* batch = (const int*)d_in[19];

    char* w = (char*)d_ws;
    size_t off = 0;
    auto alloc = [&](size_t bytes) {
        void* p = w + off;
        off += (bytes + 255) & ~(size_t)255;
        return p;
    };
    int*   flag   = (int*)  alloc(256);
    int*   deg    = (int*)  alloc((size_t)N_NODES * 4);
    int*   rs     = (int*)  alloc((size_t)(N_NODES + 1) * 4);
    float* dis    = (float*)alloc((size_t)N_NODES * 4);
    int*   csr    = (int*)  alloc((size_t)N_EDGES * 4);
    float* t      = (float*)alloc((size_t)N_NODES * 32 * 4);   // ts buffer
    float* x1     = (float*)alloc((size_t)N_NODES * 32 * 4);
    float* x2     = (float*)alloc((size_t)N_NODES * 32 * 4);
    float* x3     = (float*)alloc((size_t)N_NODES * 32 * 4);
    float* x4     = (float*)alloc((size_t)N_NODES * 4);
    int*   rank   = (int*)  alloc((size_t)N_EDGES * 4);        // per-edge slot in dst bucket
    int*   gstart = (int*)  alloc((size_t)(NGRAPH + 1) * 4);
    int*   sel    = (int*)  alloc((size_t)NGRAPH * KTOP * 4);
    int*   bsum   = (int*)  alloc(512 * 4);
    int*   bex    = (int*)  alloc(513 * 4);
    (void)ws_size; (void)n_in; (void)in_sizes; (void)out_size;

    hipMemsetAsync(deg, 0, (size_t)N_NODES * 4, stream);
    hipMemsetAsync(sel, 0xFF, (size_t)NGRAPH * KTOP * 4, stream);

    int eb = (N_EDGES + 255) / 256;
    int nb = NB_SCAN;
    int mb32 = (N_NODES + 31) / 32;   // mm kernels, 32 nodes/block
    int ab   = (N_NODES + 3) / 4;     // agg32, 4 nodes/block (wave64 each)

    k_detect<<<1, 64, 0, stream>>>(w1, flag);
    k_count_rank<<<eb, 256, 0, stream>>>(esrc, edst, deg, rank);
    k_scan1<<<nb, 256, 0, stream>>>(deg, rs, bsum);
    k_scan2<<<1, 512, 0, stream>>>(bsum, bex, nb);
    k_scan3<<<nb, 256, 0, stream>>>(rs, bex, deg, dis);
    k_gstart<<<5, 256, 0, stream>>>(batch, gstart);
    k_fill<<<eb, 256, 0, stream>>>(esrc, edst, rank, rs, csr);

    k_mm1<<<mb32, 256, 0, stream>>>(x, w1, flag, dis, t);
    k_agg32<<<ab, 256, 0, stream>>>(t, rs, csr, dis, b1, flag, x1);
    k_mm32<<<mb32, 256, 0, stream>>>(x1, w2, flag, dis, t);
    k_agg32<<<ab, 256, 0, stream>>>(t, rs, csr, dis, b2, flag, x2);
    k_mm32<<<mb32, 256, 0, stream>>>(x2, w3, flag, dis, t);
    k_agg32<<<ab, 256, 0, stream>>>(t, rs, csr, dis, b3, flag, x3);
    k_mm_out1<<<(N_NODES + 7) / 8, 256, 0, stream>>>(x3, w4, flag, dis, t);
    k_agg1<<<nb, 256, 0, stream>>>(t, rs, csr, dis, b4, flag, x4);
    k_rank<<<nb, 256, 0, stream>>>(batch, gstart, x4, sel);
    k_head<<<NGRAPH, 128, 0, stream>>>(x1, x2, x3, x4, sel, w5, b5, w6, b6,
                                       f1w, f1b, f2w, f2b, flag, (void*)d_out);
}

// Round 4
// 834.760 us; speedup vs baseline: 1.5933x; 1.2556x over previous
//
#include <hip/hip_runtime.h>
#include <hip/hip_bf16.h>

#define N_NODES 100000
#define N_EDGES 3200000
#define NGRAPH 1024
#define KTOP 30
#define NB_SCAN ((N_NODES + 255) / 256)   // 391

typedef __hip_bfloat16 bf16;

// Flag-steered load of a "float tensor" input that may be bf16 or f32 on device.
__device__ __forceinline__ float LD(const void* p, int i, int bf) {
    if (bf) {
        unsigned short h = ((const unsigned short*)p)[i];
        return __uint_as_float(((unsigned int)h) << 16);
    }
    return ((const float*)p)[i];
}

// ---------- dtype probe ----------
__global__ void k_detect(const void* w1, int* flag) {
    if (threadIdx.x == 0 && blockIdx.x == 0) {
        const unsigned short* u = (const unsigned short*)w1;
        int plausible = 0;
        for (int i = 0; i < 64; i++) {
            unsigned short h = u[2 * i];
            float v = __uint_as_float(((unsigned int)h) << 16);
            float a = fabsf(v);
            if (a == 0.f || (a >= 9.765625e-4f && a <= 2.0f)) plausible++;
        }
        *flag = (plausible >= 40) ? 1 : 0;
    }
}

// ---------- graph preprocessing ----------
__global__ void k_count_rank(const int* __restrict__ src, const int* __restrict__ dst,
                             int* __restrict__ deg, int* __restrict__ rank) {
    int e = blockIdx.x * 256 + threadIdx.x;
    if (e >= N_EDGES) return;
    int s = src[e], d = dst[e];
    int r = -1;
    if (s != d) r = atomicAdd(&deg[d], 1);
    rank[e] = r;
}

__global__ void k_scan1(const int* __restrict__ cnt, int* __restrict__ ex,
                        int* __restrict__ bsum) {
    __shared__ int sh[256];
    int i = blockIdx.x * 256 + threadIdx.x;
    int v = (i < N_NODES) ? cnt[i] : 0;
    sh[threadIdx.x] = v;
    __syncthreads();
    for (int off = 1; off < 256; off <<= 1) {
        int t = (threadIdx.x >= off) ? sh[threadIdx.x - off] : 0;
        __syncthreads();
        sh[threadIdx.x] += t;
        __syncthreads();
    }
    if (i < N_NODES) ex[i] = sh[threadIdx.x] - v;
    if (threadIdx.x == 255) bsum[blockIdx.x] = sh[255];
}

__global__ void k_scan2(const int* __restrict__ bsum, int* __restrict__ bex, int nb) {
    __shared__ int sh[512];
    int v = ((int)threadIdx.x < nb) ? bsum[threadIdx.x] : 0;
    sh[threadIdx.x] = v;
    __syncthreads();
    for (int off = 1; off < 512; off <<= 1) {
        int t = (threadIdx.x >= off) ? sh[threadIdx.x - off] : 0;
        __syncthreads();
        sh[threadIdx.x] += t;
        __syncthreads();
    }
    bex[threadIdx.x] = sh[threadIdx.x] - v;
}

__global__ void k_scan3(int* __restrict__ ex, const int* __restrict__ bex,
                        const int* __restrict__ deg, float* __restrict__ dis) {
    int i = blockIdx.x * 256 + threadIdx.x;
    if (i > N_NODES) return;
    if (i == N_NODES) { ex[N_NODES] = bex[NB_SCAN]; return; }
    ex[i] = ex[i] + bex[i >> 8];
    dis[i] = rsqrtf((float)deg[i] + 1.0f);
}

__global__ void k_gstart(const int* __restrict__ batch, int* __restrict__ gstart) {
    int g = blockIdx.x * 256 + threadIdx.x;
    if (g > NGRAPH) return;
    int lo = 0, hi = N_NODES;
    while (lo < hi) {
        int mid = (lo + hi) >> 1;
        if (batch[mid] < g) lo = mid + 1; else hi = mid;
    }
    gstart[g] = lo;
}

__global__ void k_fill(const int* __restrict__ src, const int* __restrict__ dst,
                       const int* __restrict__ rank, const int* __restrict__ rs,
                       int* __restrict__ csr) {
    int e = blockIdx.x * 256 + threadIdx.x;
    if (e >= N_EDGES) return;
    int r = rank[e];
    if (r >= 0) csr[rs[dst[e]] + r] = src[e];
}

// ---------- GCN layers (activations f32; ts = dis * (x @ W)) ----------
__global__ __launch_bounds__(256) void k_mm1(const void* __restrict__ x,
                                             const void* __restrict__ w,
                                             const int* __restrict__ flagp,
                                             const float* __restrict__ dis,
                                             float* __restrict__ ts) {
    __shared__ float Wl[128 * 32];
    __shared__ float Xs[32][128];
    int bf = *flagp;
    int tid = threadIdx.x;
    for (int idx = tid; idx < 128 * 32; idx += 256) Wl[idx] = LD(w, idx, bf);
    int nbase = blockIdx.x * 32;
    for (int idx = tid; idx < 32 * 128; idx += 256) {
        int node = nbase + (idx >> 7);
        Xs[idx >> 7][idx & 127] = (node < N_NODES) ? LD(x, node * 128 + (idx & 127), bf) : 0.f;
    }
    __syncthreads();
    int grp = tid >> 5, col = tid & 31;
    for (int rep = 0; rep < 4; rep++) {
        int sub = grp + 8 * rep;
        int node = nbase + sub;
        if (node >= N_NODES) continue;
        float acc = 0.f;
#pragma unroll 8
        for (int k = 0; k < 128; k++) acc += Xs[sub][k] * Wl[k * 32 + col];
        ts[node * 32 + col] = dis[node] * acc;
    }
}

__global__ __launch_bounds__(256) void k_mm32(const float* __restrict__ xin,
                                              const void* __restrict__ w,
                                              const int* __restrict__ flagp,
                                              const float* __restrict__ dis,
                                              float* __restrict__ ts) {
    __shared__ float Wl[32 * 32];
    __shared__ float Xs[32][32];
    int bf = *flagp;
    int tid = threadIdx.x;
    for (int idx = tid; idx < 1024; idx += 256) Wl[idx] = LD(w, idx, bf);
    int nbase = blockIdx.x * 32;
    for (int idx = tid; idx < 1024; idx += 256) {
        int node = nbase + (idx >> 5);
        Xs[idx >> 5][idx & 31] = (node < N_NODES) ? xin[node * 32 + (idx & 31)] : 0.f;
    }
    __syncthreads();
    int grp = tid >> 5, col = tid & 31;
    for (int rep = 0; rep < 4; rep++) {
        int sub = grp + 8 * rep;
        int node = nbase + sub;
        if (node >= N_NODES) continue;
        float acc = 0.f;
#pragma unroll
        for (int k = 0; k < 32; k++) acc += Xs[sub][k] * Wl[k * 32 + col];
        ts[node * 32 + col] = dis[node] * acc;
    }
}

__global__ __launch_bounds__(256) void k_mm_out1(const float* __restrict__ xin,
                                                 const void* __restrict__ w4,
                                                 const int* __restrict__ flagp,
                                                 const float* __restrict__ dis,
                                                 float* __restrict__ ts4) {
    int node = blockIdx.x * 8 + (threadIdx.x >> 5);
    int lane = threadIdx.x & 31;
    if (node >= N_NODES) return;
    int bf = *flagp;
    float v = xin[node * 32 + lane] * LD(w4, lane, bf);
    for (int off = 16; off; off >>= 1) v += __shfl_down(v, off, 32);
    if (lane == 0) ts4[node] = dis[node] * v;
}

// One wave64 per node; 8 lanes per row (float4/lane) => 8 neighbor rows in
// flight per load instruction. Cross-group reduce via shfl_xor.
__global__ __launch_bounds__(256) void k_agg32(const float4* __restrict__ ts,
                                               const int* __restrict__ rs,
                                               const int* __restrict__ csr,
                                               const float* __restrict__ dis,
                                               const void* __restrict__ b,
                                               const int* __restrict__ flagp,
                                               float4* __restrict__ out) {
    int node = blockIdx.x * 4 + (threadIdx.x >> 6);
    int lane = threadIdx.x & 63;
    int q   = lane & 7;    // quad within row: features q*4 .. q*4+3
    int grp = lane >> 3;   // neighbor group 0..7
    if (node >= N_NODES) return;
    int bf = *flagp;
    int s = rs[node], e = rs[node + 1];
    float4 acc = make_float4(0.f, 0.f, 0.f, 0.f);
    for (int i = s + grp; i < e; i += 8) {
        int v = csr[i];
        float4 m = ts[v * 8 + q];
        acc.x += m.x; acc.y += m.y; acc.z += m.z; acc.w += m.w;
    }
#pragma unroll
    for (int off = 8; off < 64; off <<= 1) {
        acc.x += __shfl_xor(acc.x, off);
        acc.y += __shfl_xor(acc.y, off);
        acc.z += __shfl_xor(acc.z, off);
        acc.w += __shfl_xor(acc.w, off);
    }
    if (grp == 0) {
        float4 self = ts[node * 8 + q];
        float d = dis[node];
        float4 r;
        r.x = tanhf(d * (acc.x + self.x) + LD(b, q * 4 + 0, bf));
        r.y = tanhf(d * (acc.y + self.y) + LD(b, q * 4 + 1, bf));
        r.z = tanhf(d * (acc.z + self.z) + LD(b, q * 4 + 2, bf));
        r.w = tanhf(d * (acc.w + self.w) + LD(b, q * 4 + 3, bf));
        out[node * 8 + q] = r;
    }
}

__global__ __launch_bounds__(256) void k_agg1(const float* __restrict__ ts4,
                                              const int* __restrict__ rs,
                                              const int* __restrict__ csr,
                                              const float* __restrict__ dis,
                                              const void* __restrict__ b4,
                                              const int* __restrict__ flagp,
                                              float* __restrict__ x4) {
    int node = blockIdx.x * 256 + threadIdx.x;
    if (node >= N_NODES) return;
    int bf = *flagp;
    int s = rs[node], e = rs[node + 1];
    float acc = ts4[node];
    for (int i = s; i < e; i++) acc += ts4[csr[i]];
    x4[node] = tanhf(dis[node] * acc + LD(b4, 0, bf));
}

// ---------- SortPooling rank ----------
__global__ __launch_bounds__(256) void k_rank(const int* __restrict__ batch,
                                              const int* __restrict__ gstart,
                                              const float* __restrict__ x4,
                                              int* __restrict__ sel) {
    int i = blockIdx.x * 256 + threadIdx.x;
    if (i >= N_NODES) return;
    int g = batch[i];
    int s = gstart[g], e = gstart[g + 1];
    float ki = x4[i];
    int rank = 0;
    for (int j = s; j < e; j++) {
        float kj = x4[j];
        rank += (kj > ki) || (kj == ki && j < i);
    }
    if (rank < KTOP) sel[g * KTOP + rank] = i;
}

// ---------- CNN/MLP head ----------
__global__ __launch_bounds__(128) void k_head(
    const float* __restrict__ x1, const float* __restrict__ x2,
    const float* __restrict__ x3, const float* __restrict__ x4,
    const int* __restrict__ sel, const void* __restrict__ w5, const void* __restrict__ b5,
    const void* __restrict__ w6, const void* __restrict__ b6,
    const void* __restrict__ f1w, const void* __restrict__ f1b,
    const void* __restrict__ f2w, const void* __restrict__ f2b,
    const int* __restrict__ flagp, void* __restrict__ out) {
    __shared__ float P[KTOP][97];
    __shared__ float H5[16][30];
    __shared__ float M[16][15];
    __shared__ float H6[352];
    __shared__ float R1[128];
    __shared__ float L[10];
    __shared__ float mls;
    int g = blockIdx.x;
    int tid = threadIdx.x;
    int bf = *flagp;

    for (int idx = tid; idx < KTOP * 97; idx += 128) {
        int p = idx / 97, f = idx - p * 97;
        int v = sel[g * KTOP + p];
        float val = 0.f;
        if (v >= 0) {
            if (f < 32)      val = x1[v * 32 + f];
            else if (f < 64) val = x2[v * 32 + f - 32];
            else if (f < 96) val = x3[v * 32 + f - 64];
            else             val = x4[v];
        }
        P[p][f] = val;
    }
    __syncthreads();
    for (int idx = tid; idx < 480; idx += 128) {   // conv5 + relu
        int o = idx / 30, p = idx - o * 30;
        float acc = LD(b5, o, bf);
        for (int f = 0; f < 97; f++) acc += LD(w5, o * 97 + f, bf) * P[p][f];
        H5[o][p] = fmaxf(acc, 0.f);
    }
    __syncthreads();
    for (int idx = tid; idx < 240; idx += 128) {   // maxpool2
        int o = idx / 15, q = idx - o * 15;
        M[o][q] = fmaxf(H5[o][2 * q], H5[o][2 * q + 1]);
    }
    __syncthreads();
    for (int idx = tid; idx < 352; idx += 128) {   // conv6 + relu
        int oc = idx / 11, tp = idx - oc * 11;
        float acc = LD(b6, oc, bf);
        for (int ic = 0; ic < 16; ic++) {
#pragma unroll
            for (int k = 0; k < 5; k++)
                acc += LD(w6, (oc * 16 + ic) * 5 + k, bf) * M[ic][tp + k];
        }
        H6[idx] = fmaxf(acc, 0.f);
    }
    __syncthreads();
    {   // fc1 + relu
        float acc = LD(f1b, tid, bf);
        for (int i = 0; i < 352; i++) acc += H6[i] * LD(f1w, i * 128 + tid, bf);
        R1[tid] = fmaxf(acc, 0.f);
    }
    __syncthreads();
    if (tid < 10) {   // fc2
        float acc = LD(f2b, tid, bf);
        for (int k = 0; k < 128; k++) acc += R1[k] * LD(f2w, k * 10 + tid, bf);
        L[tid] = acc;
    }
    __syncthreads();
    if (tid == 0) {
        float m = L[0];
        for (int c = 1; c < 10; c++) m = fmaxf(m, L[c]);
        float ssum = 0.f;
        for (int c = 0; c < 10; c++) ssum += expf(L[c] - m);
        mls = m + logf(ssum);
    }
    __syncthreads();
    if (tid < 10) {
        float v = L[tid] - mls;
        if (bf) ((bf16*)out)[g * 10 + tid] = __float2bfloat16(v);
        else    ((float*)out)[g * 10 + tid] = v;
    }
}

extern "C" void kernel_launch(void* const* d_in, const int* in_sizes, int n_in,
                              void* d_out, int out_size, void* d_ws, size_t ws_size,
                              hipStream_t stream) {
    const void* x   = d_in[0];
    const void* w1  = d_in[1];  const void* b1  = d_in[2];
    const void* w2  = d_in[3];  const void* b2  = d_in[4];
    const void* w3  = d_in[5];  const void* b3  = d_in[6];
    const void* w4  = d_in[7];  const void* b4  = d_in[8];
    const void* w5  = d_in[9];  const void* b5  = d_in[10];
    const void* w6  = d_in[11]; const void* b6  = d_in[12];
    const void* f1w = d_in[13]; const void* f1b = d_in[14];
    const void* f2w = d_in[15]; const void* f2b = d_in[16];
    const int* esrc  = (const int*)d_in[17];
    const int* edst  = (const int*)d_in[18];
    const int* batch = (const int*)d_in[19];

    char* w = (char*)d_ws;
    size_t off = 0;
    auto alloc = [&](size_t bytes) {
        void* p = w + off;
        off += (bytes + 255) & ~(size_t)255;
        return p;
    };
    int*   flag   = (int*)  alloc(256);
    int*   deg    = (int*)  alloc((size_t)N_NODES * 4);
    int*   rs     = (int*)  alloc((size_t)(N_NODES + 1) * 4);
    float* dis    = (float*)alloc((size_t)N_NODES * 4);
    int*   csr    = (int*)  alloc((size_t)N_EDGES * 4);
    float* t      = (float*)alloc((size_t)N_NODES * 32 * 4);   // ts buffer
    float* x1     = (float*)alloc((size_t)N_NODES * 32 * 4);
    float* x2     = (float*)alloc((size_t)N_NODES * 32 * 4);
    float* x3     = (float*)alloc((size_t)N_NODES * 32 * 4);
    float* x4     = (float*)alloc((size_t)N_NODES * 4);
    int*   rank   = (int*)  alloc((size_t)N_EDGES * 4);
    int*   gstart = (int*)  alloc((size_t)(NGRAPH + 1) * 4);
    int*   sel    = (int*)  alloc((size_t)NGRAPH * KTOP * 4);
    int*   bsum   = (int*)  alloc(512 * 4);
    int*   bex    = (int*)  alloc(513 * 4);
    (void)ws_size; (void)n_in; (void)in_sizes; (void)out_size;

    hipMemsetAsync(deg, 0, (size_t)N_NODES * 4, stream);
    hipMemsetAsync(sel, 0xFF, (size_t)NGRAPH * KTOP * 4, stream);

    int eb = (N_EDGES + 255) / 256;
    int nb = NB_SCAN;
    int mb32 = (N_NODES + 31) / 32;
    int ab   = (N_NODES + 3) / 4;

    k_detect<<<1, 64, 0, stream>>>(w1, flag);
    k_count_rank<<<eb, 256, 0, stream>>>(esrc, edst, deg, rank);
    k_scan1<<<nb, 256, 0, stream>>>(deg, rs, bsum);
    k_scan2<<<1, 512, 0, stream>>>(bsum, bex, nb);
    k_scan3<<<nb, 256, 0, stream>>>(rs, bex, deg, dis);
    k_gstart<<<5, 256, 0, stream>>>(batch, gstart);
    k_fill<<<eb, 256, 0, stream>>>(esrc, edst, rank, rs, csr);

    k_mm1<<<mb32, 256, 0, stream>>>(x, w1, flag, dis, t);
    k_agg32<<<ab, 256, 0, stream>>>((const float4*)t, rs, csr, dis, b1, flag, (float4*)x1);
    k_mm32<<<mb32, 256, 0, stream>>>(x1, w2, flag, dis, t);
    k_agg32<<<ab, 256, 0, stream>>>((const float4*)t, rs, csr, dis, b2, flag, (float4*)x2);
    k_mm32<<<mb32, 256, 0, stream>>>(x2, w3, flag, dis, t);
    k_agg32<<<ab, 256, 0, stream>>>((const float4*)t, rs, csr, dis, b3, flag, (float4*)x3);
    k_mm_out1<<<(N_NODES + 7) / 8, 256, 0, stream>>>(x3, w4, flag, dis, t);
    k_agg1<<<nb, 256, 0, stream>>>(t, rs, csr, dis, b4, flag, x4);
    k_rank<<<nb, 256, 0, stream>>>(batch, gstart, x4, sel);
    k_head<<<NGRAPH, 128, 0, stream>>>(x1, x2, x3, x4, sel, w5, b5, w6, b6,
                                       f1w, f1b, f2w, f2b, flag, (void*)d_out);
}

// Round 5
// 799.606 us; speedup vs baseline: 1.6633x; 1.0440x over previous
//
#include <hip/hip_runtime.h>
#include <hip/hip_bf16.h>

#define N_NODES 100000
#define N_EDGES 3200000
#define NGRAPH 1024
#define KTOP 30
#define NB_SCAN ((N_NODES + 255) / 256)   // 391
#define EPT 8                              // edges per thread in edge kernels

typedef __hip_bfloat16 bf16;

__device__ __forceinline__ float u2f(unsigned short h) {
    return __uint_as_float(((unsigned int)h) << 16);
}
// Flag-steered scalar load of a float-tensor input that may be bf16 or f32.
__device__ __forceinline__ float LD(const void* p, int i, int bf) {
    if (bf) return u2f(((const unsigned short*)p)[i]);
    return ((const float*)p)[i];
}

// ---------- dtype probe ----------
__global__ void k_detect(const void* w1, int* flag) {
    if (threadIdx.x == 0 && blockIdx.x == 0) {
        const unsigned short* u = (const unsigned short*)w1;
        int plausible = 0;
        for (int i = 0; i < 64; i++) {
            float a = fabsf(u2f(u[2 * i]));
            if (a == 0.f || (a >= 9.765625e-4f && a <= 2.0f)) plausible++;
        }
        *flag = (plausible >= 40) ? 1 : 0;
    }
}

// ---------- graph preprocessing ----------
// Pass A: 8 edges/thread -> 8 independent atomics in flight per lane.
__global__ void k_count_rank(const int* __restrict__ src, const int* __restrict__ dst,
                             int* __restrict__ deg, int* __restrict__ rank) {
    int base = blockIdx.x * (256 * EPT) + threadIdx.x;
    int r[EPT];
#pragma unroll
    for (int j = 0; j < EPT; j++) {
        int e = base + j * 256;
        r[j] = -1;
        if (e < N_EDGES) {
            int s = src[e], d = dst[e];
            if (s != d) r[j] = atomicAdd(&deg[d], 1);
        }
    }
#pragma unroll
    for (int j = 0; j < EPT; j++) {
        int e = base + j * 256;
        if (e < N_EDGES) rank[e] = r[j];
    }
}

__global__ void k_scan1(const int* __restrict__ cnt, int* __restrict__ ex,
                        int* __restrict__ bsum) {
    __shared__ int sh[256];
    int i = blockIdx.x * 256 + threadIdx.x;
    int v = (i < N_NODES) ? cnt[i] : 0;
    sh[threadIdx.x] = v;
    __syncthreads();
    for (int off = 1; off < 256; off <<= 1) {
        int t = (threadIdx.x >= off) ? sh[threadIdx.x - off] : 0;
        __syncthreads();
        sh[threadIdx.x] += t;
        __syncthreads();
    }
    if (i < N_NODES) ex[i] = sh[threadIdx.x] - v;
    if (threadIdx.x == 255) bsum[blockIdx.x] = sh[255];
}

__global__ void k_scan2(const int* __restrict__ bsum, int* __restrict__ bex, int nb) {
    __shared__ int sh[512];
    int v = ((int)threadIdx.x < nb) ? bsum[threadIdx.x] : 0;
    sh[threadIdx.x] = v;
    __syncthreads();
    for (int off = 1; off < 512; off <<= 1) {
        int t = (threadIdx.x >= off) ? sh[threadIdx.x - off] : 0;
        __syncthreads();
        sh[threadIdx.x] += t;
        __syncthreads();
    }
    bex[threadIdx.x] = sh[threadIdx.x] - v;
}

__global__ void k_scan3(int* __restrict__ ex, const int* __restrict__ bex,
                        const int* __restrict__ deg, float* __restrict__ dis) {
    int i = blockIdx.x * 256 + threadIdx.x;
    if (i > N_NODES) return;
    if (i == N_NODES) { ex[N_NODES] = bex[NB_SCAN]; return; }
    ex[i] = ex[i] + bex[i >> 8];
    dis[i] = rsqrtf((float)deg[i] + 1.0f);
}

__global__ void k_gstart(const int* __restrict__ batch, int* __restrict__ gstart) {
    int g = blockIdx.x * 256 + threadIdx.x;
    if (g > NGRAPH) return;
    int lo = 0, hi = N_NODES;
    while (lo < hi) {
        int mid = (lo + hi) >> 1;
        if (batch[mid] < g) lo = mid + 1; else hi = mid;
    }
    gstart[g] = lo;
}

// Pass B: pure scatter; 8 independent chains per lane.
__global__ void k_fill(const int* __restrict__ src, const int* __restrict__ dst,
                       const int* __restrict__ rank, const int* __restrict__ rs,
                       int* __restrict__ csr) {
    int base = blockIdx.x * (256 * EPT) + threadIdx.x;
#pragma unroll
    for (int j = 0; j < EPT; j++) {
        int e = base + j * 256;
        if (e < N_EDGES) {
            int r = rank[e];
            if (r >= 0) csr[rs[dst[e]] + r] = src[e];
        }
    }
}

// ---------- GCN layers (activations f32; ts = dis * (x @ W)) ----------
__global__ __launch_bounds__(256) void k_mm1(const void* __restrict__ x,
                                             const void* __restrict__ w,
                                             const int* __restrict__ flagp,
                                             const float* __restrict__ dis,
                                             float* __restrict__ ts) {
    __shared__ float Wl[128 * 32];
    __shared__ float Xs[32][128];
    int bf = *flagp;
    int tid = threadIdx.x;
    int nbase = blockIdx.x * 32;          // N_NODES % 32 == 0: always full
    if (bf) {
        const ushort4* wv = (const ushort4*)w;
        for (int idx = tid; idx < 1024; idx += 256) {
            ushort4 h = wv[idx];
            int p = idx * 4;
            Wl[p] = u2f(h.x); Wl[p + 1] = u2f(h.y); Wl[p + 2] = u2f(h.z); Wl[p + 3] = u2f(h.w);
        }
        const ushort4* xv = (const ushort4*)x;
        for (int idx = tid; idx < 1024; idx += 256) {
            int nd = idx >> 5, q = idx & 31;
            ushort4 h = xv[(size_t)(nbase + nd) * 32 + q];
            float* d = &Xs[nd][q * 4];
            d[0] = u2f(h.x); d[1] = u2f(h.y); d[2] = u2f(h.z); d[3] = u2f(h.w);
        }
    } else {
        const float* wf = (const float*)w;
        for (int idx = tid; idx < 4096; idx += 256) Wl[idx] = wf[idx];
        const float* xf = (const float*)x;
        for (int idx = tid; idx < 4096; idx += 256)
            Xs[idx >> 7][idx & 127] = xf[(size_t)nbase * 128 + idx];
    }
    __syncthreads();
    int grp = tid >> 5, col = tid & 31;
    for (int rep = 0; rep < 4; rep++) {
        int sub = grp + 8 * rep;
        int node = nbase + sub;
        float acc = 0.f;
#pragma unroll 8
        for (int k = 0; k < 128; k++) acc += Xs[sub][k] * Wl[k * 32 + col];
        ts[node * 32 + col] = dis[node] * acc;
    }
}

__global__ __launch_bounds__(256) void k_mm32(const float* __restrict__ xin,
                                              const void* __restrict__ w,
                                              const int* __restrict__ flagp,
                                              const float* __restrict__ dis,
                                              float* __restrict__ ts) {
    __shared__ float Wl[32 * 32];
    __shared__ float Xs[32][32];
    int bf = *flagp;
    int tid = threadIdx.x;
    int nbase = blockIdx.x * 32;
    if (bf) {
        const ushort4* wv = (const ushort4*)w;
        for (int idx = tid; idx < 256; idx += 256) {
            ushort4 h = wv[idx];
            int p = idx * 4;
            Wl[p] = u2f(h.x); Wl[p + 1] = u2f(h.y); Wl[p + 2] = u2f(h.z); Wl[p + 3] = u2f(h.w);
        }
    } else {
        const float* wf = (const float*)w;
        for (int idx = tid; idx < 1024; idx += 256) Wl[idx] = wf[idx];
    }
    {
        const float4* xv = (const float4*)xin;
        int nd = tid >> 3, q = tid & 7;
        float4 v = xv[(size_t)(nbase + nd) * 8 + q];
        float* d = &Xs[nd][q * 4];
        d[0] = v.x; d[1] = v.y; d[2] = v.z; d[3] = v.w;
    }
    __syncthreads();
    int grp = tid >> 5, col = tid & 31;
    for (int rep = 0; rep < 4; rep++) {
        int sub = grp + 8 * rep;
        int node = nbase + sub;
        float acc = 0.f;
#pragma unroll
        for (int k = 0; k < 32; k++) acc += Xs[sub][k] * Wl[k * 32 + col];
        ts[node * 32 + col] = dis[node] * acc;
    }
}

__global__ __launch_bounds__(256) void k_mm_out1(const float* __restrict__ xin,
                                                 const void* __restrict__ w4,
                                                 const int* __restrict__ flagp,
                                                 const float* __restrict__ dis,
                                                 float* __restrict__ ts4) {
    int node = blockIdx.x * 8 + (threadIdx.x >> 5);
    int lane = threadIdx.x & 31;
    if (node >= N_NODES) return;
    int bf = *flagp;
    float v = xin[node * 32 + lane] * LD(w4, lane, bf);
    for (int off = 16; off; off >>= 1) v += __shfl_down(v, off, 32);
    if (lane == 0) ts4[node] = dis[node] * v;
}

// One wave64 per node; 8 lanes per row (float4/lane) => 8 neighbor rows in
// flight per load instruction. Cross-group reduce via shfl_xor.
__global__ __launch_bounds__(256) void k_agg32(const float4* __restrict__ ts,
                                               const int* __restrict__ rs,
                                               const int* __restrict__ csr,
                                               const float* __restrict__ dis,
                                               const void* __restrict__ b,
                                               const int* __restrict__ flagp,
                                               float4* __restrict__ out) {
    int node = blockIdx.x * 4 + (threadIdx.x >> 6);
    int lane = threadIdx.x & 63;
    int q   = lane & 7;
    int grp = lane >> 3;
    int bf = *flagp;
    int s = rs[node], e = rs[node + 1];
    float4 acc = make_float4(0.f, 0.f, 0.f, 0.f);
    for (int i = s + grp; i < e; i += 8) {
        int v = csr[i];
        float4 m = ts[v * 8 + q];
        acc.x += m.x; acc.y += m.y; acc.z += m.z; acc.w += m.w;
    }
#pragma unroll
    for (int off = 8; off < 64; off <<= 1) {
        acc.x += __shfl_xor(acc.x, off);
        acc.y += __shfl_xor(acc.y, off);
        acc.z += __shfl_xor(acc.z, off);
        acc.w += __shfl_xor(acc.w, off);
    }
    if (grp == 0) {
        float4 self = ts[node * 8 + q];
        float d = dis[node];
        float4 r;
        r.x = tanhf(d * (acc.x + self.x) + LD(b, q * 4 + 0, bf));
        r.y = tanhf(d * (acc.y + self.y) + LD(b, q * 4 + 1, bf));
        r.z = tanhf(d * (acc.z + self.z) + LD(b, q * 4 + 2, bf));
        r.w = tanhf(d * (acc.w + self.w) + LD(b, q * 4 + 3, bf));
        out[node * 8 + q] = r;
    }
}

// 16 lanes per node: 2 gathers/lane instead of 32 serial.
__global__ __launch_bounds__(256) void k_agg1(const float* __restrict__ ts4,
                                              const int* __restrict__ rs,
                                              const int* __restrict__ csr,
                                              const float* __restrict__ dis,
                                              const void* __restrict__ b4,
                                              const int* __restrict__ flagp,
                                              float* __restrict__ x4) {
    int node = blockIdx.x * 16 + (threadIdx.x >> 4);
    int lane = threadIdx.x & 15;
    int s = rs[node], e = rs[node + 1];
    float acc = 0.f;
    for (int i = s + lane; i < e; i += 16) acc += ts4[csr[i]];
#pragma unroll
    for (int off = 1; off < 16; off <<= 1) acc += __shfl_xor(acc, off);
    if (lane == 0) {
        int bf = *flagp;
        x4[node] = tanhf(dis[node] * (acc + ts4[node]) + LD(b4, 0, bf));
    }
}

// ---------- SortPooling rank ----------
__global__ __launch_bounds__(256) void k_rank(const int* __restrict__ batch,
                                              const int* __restrict__ gstart,
                                              const float* __restrict__ x4,
                                              int* __restrict__ sel) {
    int i = blockIdx.x * 256 + threadIdx.x;
    if (i >= N_NODES) return;
    int g = batch[i];
    int s = gstart[g], e = gstart[g + 1];
    float ki = x4[i];
    int rank = 0;
    for (int j = s; j < e; j++) {
        float kj = x4[j];
        rank += (kj > ki) || (kj == ki && j < i);
    }
    if (rank < KTOP) sel[g * KTOP + rank] = i;
}

// ---------- CNN/MLP head ----------
__global__ __launch_bounds__(128) void k_head(
    const float* __restrict__ x1, const float* __restrict__ x2,
    const float* __restrict__ x3, const float* __restrict__ x4,
    const int* __restrict__ sel, const void* __restrict__ w5, const void* __restrict__ b5,
    const void* __restrict__ w6, const void* __restrict__ b6,
    const void* __restrict__ f1w, const void* __restrict__ f1b,
    const void* __restrict__ f2w, const void* __restrict__ f2b,
    const int* __restrict__ flagp, void* __restrict__ out) {
    __shared__ float P[KTOP][97];
    __shared__ float H5[16][30];
    __shared__ float M[16][15];
    __shared__ float H6[352];
    __shared__ float R1[128];
    __shared__ float L[10];
    __shared__ float mls;
    int g = blockIdx.x;
    int tid = threadIdx.x;
    int bf = *flagp;

    for (int idx = tid; idx < KTOP * 97; idx += 128) {
        int p = idx / 97, f = idx - p * 97;
        int v = sel[g * KTOP + p];
        float val = 0.f;
        if (v >= 0) {
            if (f < 32)      val = x1[v * 32 + f];
            else if (f < 64) val = x2[v * 32 + f - 32];
            else if (f < 96) val = x3[v * 32 + f - 64];
            else             val = x4[v];
        }
        P[p][f] = val;
    }
    __syncthreads();
    for (int idx = tid; idx < 480; idx += 128) {   // conv5 + relu
        int o = idx / 30, p = idx - o * 30;
        float acc = LD(b5, o, bf);
        for (int f = 0; f < 97; f++) acc += LD(w5, o * 97 + f, bf) * P[p][f];
        H5[o][p] = fmaxf(acc, 0.f);
    }
    __syncthreads();
    for (int idx = tid; idx < 240; idx += 128) {   // maxpool2
        int o = idx / 15, q = idx - o * 15;
        M[o][q] = fmaxf(H5[o][2 * q], H5[o][2 * q + 1]);
    }
    __syncthreads();
    for (int idx = tid; idx < 352; idx += 128) {   // conv6 + relu
        int oc = idx / 11, tp = idx - oc * 11;
        float acc = LD(b6, oc, bf);
        for (int ic = 0; ic < 16; ic++) {
#pragma unroll
            for (int k = 0; k < 5; k++)
                acc += LD(w6, (oc * 16 + ic) * 5 + k, bf) * M[ic][tp + k];
        }
        H6[idx] = fmaxf(acc, 0.f);
    }
    __syncthreads();
    {   // fc1 + relu
        float acc = LD(f1b, tid, bf);
        for (int i = 0; i < 352; i++) acc += H6[i] * LD(f1w, i * 128 + tid, bf);
        R1[tid] = fmaxf(acc, 0.f);
    }
    __syncthreads();
    if (tid < 10) {   // fc2
        float acc = LD(f2b, tid, bf);
        for (int k = 0; k < 128; k++) acc += R1[k] * LD(f2w, k * 10 + tid, bf);
        L[tid] = acc;
    }
    __syncthreads();
    if (tid == 0) {
        float m = L[0];
        for (int c = 1; c < 10; c++) m = fmaxf(m, L[c]);
        float ssum = 0.f;
        for (int c = 0; c < 10; c++) ssum += expf(L[c] - m);
        mls = m + logf(ssum);
    }
    __syncthreads();
    if (tid < 10) {
        float v = L[tid] - mls;
        if (bf) ((bf16*)out)[g * 10 + tid] = __float2bfloat16(v);
        else    ((float*)out)[g * 10 + tid] = v;
    }
}

extern "C" void kernel_launch(void* const* d_in, const int* in_sizes, int n_in,
                              void* d_out, int out_size, void* d_ws, size_t ws_size,
                              hipStream_t stream) {
    const void* x   = d_in[0];
    const void* w1  = d_in[1];  const void* b1  = d_in[2];
    const void* w2  = d_in[3];  const void* b2  = d_in[4];
    const void* w3  = d_in[5];  const void* b3  = d_in[6];
    const void* w4  = d_in[7];  const void* b4  = d_in[8];
    const void* w5  = d_in[9];  const void* b5  = d_in[10];
    const void* w6  = d_in[11]; const void* b6  = d_in[12];
    const void* f1w = d_in[13]; const void* f1b = d_in[14];
    const void* f2w = d_in[15]; const void* f2b = d_in[16];
    const int* esrc  = (const int*)d_in[17];
    const int* edst  = (const int*)d_in[18];
    const int* batch = (const int*)d_in[19];

    char* w = (char*)d_ws;
    size_t off = 0;
    auto alloc = [&](size_t bytes) {
        void* p = w + off;
        off += (bytes + 255) & ~(size_t)255;
        return p;
    };
    int*   flag   = (int*)  alloc(256);
    int*   deg    = (int*)  alloc((size_t)N_NODES * 4);
    int*   rs     = (int*)  alloc((size_t)(N_NODES + 1) * 4);
    float* dis    = (float*)alloc((size_t)N_NODES * 4);
    int*   csr    = (int*)  alloc((size_t)N_EDGES * 4);
    float* t      = (float*)alloc((size_t)N_NODES * 32 * 4);
    float* x1     = (float*)alloc((size_t)N_NODES * 32 * 4);
    float* x2     = (float*)alloc((size_t)N_NODES * 32 * 4);
    float* x3     = (float*)alloc((size_t)N_NODES * 32 * 4);
    float* x4     = (float*)alloc((size_t)N_NODES * 4);
    int*   rank   = (int*)  alloc((size_t)N_EDGES * 4);
    int*   gstart = (int*)  alloc((size_t)(NGRAPH + 1) * 4);
    int*   sel    = (int*)  alloc((size_t)NGRAPH * KTOP * 4);
    int*   bsum   = (int*)  alloc(512 * 4);
    int*   bex    = (int*)  alloc(513 * 4);
    (void)ws_size; (void)n_in; (void)in_sizes; (void)out_size;

    hipMemsetAsync(deg, 0, (size_t)N_NODES * 4, stream);
    hipMemsetAsync(sel, 0xFF, (size_t)NGRAPH * KTOP * 4, stream);

    int eb8  = (N_EDGES + 256 * EPT - 1) / (256 * EPT);
    int nb   = NB_SCAN;
    int mb32 = N_NODES / 32;          // 3125, exact
    int ab   = N_NODES / 4;           // 25000, exact
    int a1b  = N_NODES / 16;          // 6250, exact

    k_detect<<<1, 64, 0, stream>>>(w1, flag);
    k_count_rank<<<eb8, 256, 0, stream>>>(esrc, edst, deg, rank);
    k_scan1<<<nb, 256, 0, stream>>>(deg, rs, bsum);
    k_scan2<<<1, 512, 0, stream>>>(bsum, bex, nb);
    k_scan3<<<nb, 256, 0, stream>>>(rs, bex, deg, dis);
    k_gstart<<<5, 256, 0, stream>>>(batch, gstart);
    k_fill<<<eb8, 256, 0, stream>>>(esrc, edst, rank, rs, csr);

    k_mm1<<<mb32, 256, 0, stream>>>(x, w1, flag, dis, t);
    k_agg32<<<ab, 256, 0, stream>>>((const float4*)t, rs, csr, dis, b1, flag, (float4*)x1);
    k_mm32<<<mb32, 256, 0, stream>>>(x1, w2, flag, dis, t);
    k_agg32<<<ab, 256, 0, stream>>>((const float4*)t, rs, csr, dis, b2, flag, (float4*)x2);
    k_mm32<<<mb32, 256, 0, stream>>>(x2, w3, flag, dis, t);
    k_agg32<<<ab, 256, 0, stream>>>((const float4*)t, rs, csr, dis, b3, flag, (float4*)x3);
    k_mm_out1<<<(N_NODES + 7) / 8, 256, 0, stream>>>(x3, w4, flag, dis, t);
    k_agg1<<<a1b, 256, 0, stream>>>(t, rs, csr, dis, b4, flag, x4);
    k_rank<<<nb, 256, 0, stream>>>(batch, gstart, x4, sel);
    k_head<<<NGRAPH, 128, 0, stream>>>(x1, x2, x3, x4, sel, w5, b5, w6, b6,
                                       f1w, f1b, f2w, f2b, flag, (void*)d_out);
}

// Round 7
// 768.910 us; speedup vs baseline: 1.7297x; 1.0399x over previous
//
#include <hip/hip_runtime.h>
#include <hip/hip_bf16.h>

#define N_NODES 100000
#define N_EDGES 3200000
#define NGRAPH 1024
#define KTOP 30
#define NB_SCAN ((N_NODES + 255) / 256)   // 391
#define EPT 8                              // edges per thread in edge kernels
#define PELEM (NGRAPH * KTOP * 97)         // pooled tensor elements

typedef __hip_bfloat16 bf16;

__device__ __forceinline__ float u2f(unsigned short h) {
    return __uint_as_float(((unsigned int)h) << 16);
}
// Flag-steered scalar load of a float-tensor input that may be bf16 or f32.
__device__ __forceinline__ float LD(const void* p, int i, int bf) {
    if (bf) return u2f(((const unsigned short*)p)[i]);
    return ((const float*)p)[i];
}

// ---------- dtype probe ----------
__global__ void k_detect(const void* w1, int* flag) {
    if (threadIdx.x == 0 && blockIdx.x == 0) {
        const unsigned short* u = (const unsigned short*)w1;
        int plausible = 0;
        for (int i = 0; i < 64; i++) {
            float a = fabsf(u2f(u[2 * i]));
            if (a == 0.f || (a >= 9.765625e-4f && a <= 2.0f)) plausible++;
        }
        *flag = (plausible >= 40) ? 1 : 0;
    }
}

// ---------- graph preprocessing ----------
__global__ void k_count_rank(const int* __restrict__ src, const int* __restrict__ dst,
                             int* __restrict__ deg, int* __restrict__ rank) {
    int base = blockIdx.x * (256 * EPT) + threadIdx.x;
    int r[EPT];
#pragma unroll
    for (int j = 0; j < EPT; j++) {
        int e = base + j * 256;
        r[j] = -1;
        if (e < N_EDGES) {
            int s = src[e], d = dst[e];
            if (s != d) r[j] = atomicAdd(&deg[d], 1);
        }
    }
#pragma unroll
    for (int j = 0; j < EPT; j++) {
        int e = base + j * 256;
        if (e < N_EDGES) rank[e] = r[j];
    }
}

__global__ void k_scan1(const int* __restrict__ cnt, int* __restrict__ ex,
                        int* __restrict__ bsum) {
    __shared__ int sh[256];
    int i = blockIdx.x * 256 + threadIdx.x;
    int v = (i < N_NODES) ? cnt[i] : 0;
    sh[threadIdx.x] = v;
    __syncthreads();
    for (int off = 1; off < 256; off <<= 1) {
        int t = (threadIdx.x >= off) ? sh[threadIdx.x - off] : 0;
        __syncthreads();
        sh[threadIdx.x] += t;
        __syncthreads();
    }
    if (i < N_NODES) ex[i] = sh[threadIdx.x] - v;
    if (threadIdx.x == 255) bsum[blockIdx.x] = sh[255];
}

__global__ void k_scan2(const int* __restrict__ bsum, int* __restrict__ bex, int nb) {
    __shared__ int sh[512];
    int v = ((int)threadIdx.x < nb) ? bsum[threadIdx.x] : 0;
    sh[threadIdx.x] = v;
    __syncthreads();
    for (int off = 1; off < 512; off <<= 1) {
        int t = (threadIdx.x >= off) ? sh[threadIdx.x - off] : 0;
        __syncthreads();
        sh[threadIdx.x] += t;
        __syncthreads();
    }
    bex[threadIdx.x] = sh[threadIdx.x] - v;
}

__global__ void k_scan3(int* __restrict__ ex, const int* __restrict__ bex,
                        const int* __restrict__ deg, float* __restrict__ dis) {
    int i = blockIdx.x * 256 + threadIdx.x;
    if (i > N_NODES) return;
    if (i == N_NODES) { ex[N_NODES] = bex[NB_SCAN]; return; }
    ex[i] = ex[i] + bex[i >> 8];
    dis[i] = rsqrtf((float)deg[i] + 1.0f);
}

__global__ void k_gstart(const int* __restrict__ batch, int* __restrict__ gstart) {
    int g = blockIdx.x * 256 + threadIdx.x;
    if (g > NGRAPH) return;
    int lo = 0, hi = N_NODES;
    while (lo < hi) {
        int mid = (lo + hi) >> 1;
        if (batch[mid] < g) lo = mid + 1; else hi = mid;
    }
    gstart[g] = lo;
}

__global__ void k_fill(const int* __restrict__ src, const int* __restrict__ dst,
                       const int* __restrict__ rank, const int* __restrict__ rs,
                       int* __restrict__ csr) {
    int base = blockIdx.x * (256 * EPT) + threadIdx.x;
#pragma unroll
    for (int j = 0; j < EPT; j++) {
        int e = base + j * 256;
        if (e < N_EDGES) {
            int r = rank[e];
            if (r >= 0) csr[rs[dst[e]] + r] = src[e];
        }
    }
}

// ---------- GCN layers (activations f32; ts = dis * (x @ W)) ----------
__global__ __launch_bounds__(256) void k_mm1(const void* __restrict__ x,
                                             const void* __restrict__ w,
                                             const int* __restrict__ flagp,
                                             const float* __restrict__ dis,
                                             float* __restrict__ ts) {
    __shared__ float Wl[128 * 32];
    __shared__ float Xs[32][128];
    int bf = *flagp;
    int tid = threadIdx.x;
    int nbase = blockIdx.x * 32;          // N_NODES % 32 == 0: always full
    if (bf) {
        const ushort4* wv = (const ushort4*)w;
        for (int idx = tid; idx < 1024; idx += 256) {
            ushort4 h = wv[idx];
            int p = idx * 4;
            Wl[p] = u2f(h.x); Wl[p + 1] = u2f(h.y); Wl[p + 2] = u2f(h.z); Wl[p + 3] = u2f(h.w);
        }
        const ushort4* xv = (const ushort4*)x;
        for (int idx = tid; idx < 1024; idx += 256) {
            int nd = idx >> 5, q = idx & 31;
            ushort4 h = xv[(size_t)(nbase + nd) * 32 + q];
            float* d = &Xs[nd][q * 4];
            d[0] = u2f(h.x); d[1] = u2f(h.y); d[2] = u2f(h.z); d[3] = u2f(h.w);
        }
    } else {
        const float* wf = (const float*)w;
        for (int idx = tid; idx < 4096; idx += 256) Wl[idx] = wf[idx];
        const float* xf = (const float*)x;
        for (int idx = tid; idx < 4096; idx += 256)
            Xs[idx >> 7][idx & 127] = xf[(size_t)nbase * 128 + idx];
    }
    __syncthreads();
    int grp = tid >> 5, col = tid & 31;
    for (int rep = 0; rep < 4; rep++) {
        int sub = grp + 8 * rep;
        int node = nbase + sub;
        float acc = 0.f;
#pragma unroll 8
        for (int k = 0; k < 128; k++) acc += Xs[sub][k] * Wl[k * 32 + col];
        ts[node * 32 + col] = dis[node] * acc;
    }
}

__global__ __launch_bounds__(256) void k_mm32(const float* __restrict__ xin,
                                              const void* __restrict__ w,
                                              const int* __restrict__ flagp,
                                              const float* __restrict__ dis,
                                              float* __restrict__ ts) {
    __shared__ float Wl[32 * 32];
    __shared__ float Xs[32][32];
    int bf = *flagp;
    int tid = threadIdx.x;
    int nbase = blockIdx.x * 32;
    if (bf) {
        const ushort4* wv = (const ushort4*)w;
        for (int idx = tid; idx < 256; idx += 256) {
            ushort4 h = wv[idx];
            int p = idx * 4;
            Wl[p] = u2f(h.x); Wl[p + 1] = u2f(h.y); Wl[p + 2] = u2f(h.z); Wl[p + 3] = u2f(h.w);
        }
    } else {
        const float* wf = (const float*)w;
        for (int idx = tid; idx < 1024; idx += 256) Wl[idx] = wf[idx];
    }
    {
        const float4* xv = (const float4*)xin;
        int nd = tid >> 3, q = tid & 7;
        float4 v = xv[(size_t)(nbase + nd) * 8 + q];
        float* d = &Xs[nd][q * 4];
        d[0] = v.x; d[1] = v.y; d[2] = v.z; d[3] = v.w;
    }
    __syncthreads();
    int grp = tid >> 5, col = tid & 31;
    for (int rep = 0; rep < 4; rep++) {
        int sub = grp + 8 * rep;
        int node = nbase + sub;
        float acc = 0.f;
#pragma unroll
        for (int k = 0; k < 32; k++) acc += Xs[sub][k] * Wl[k * 32 + col];
        ts[node * 32 + col] = dis[node] * acc;
    }
}

__global__ __launch_bounds__(256) void k_mm_out1(const float* __restrict__ xin,
                                                 const void* __restrict__ w4,
                                                 const int* __restrict__ flagp,
                                                 const float* __restrict__ dis,
                                                 float* __restrict__ ts4) {
    int node = blockIdx.x * 8 + (threadIdx.x >> 5);
    int lane = threadIdx.x & 31;
    if (node >= N_NODES) return;
    int bf = *flagp;
    float v = xin[node * 32 + lane] * LD(w4, lane, bf);
    for (int off = 16; off; off >>= 1) v += __shfl_down(v, off, 32);
    if (lane == 0) ts4[node] = dis[node] * v;
}

// One wave64 per node; 8 lanes per row (float4/lane) => 8 neighbor rows in
// flight per load instruction. Cross-group reduce via shfl_xor.
__global__ __launch_bounds__(256) void k_agg32(const float4* __restrict__ ts,
                                               const int* __restrict__ rs,
                                               const int* __restrict__ csr,
                                               const float* __restrict__ dis,
                                               const void* __restrict__ b,
                                               const int* __restrict__ flagp,
                                               float4* __restrict__ out) {
    int node = blockIdx.x * 4 + (threadIdx.x >> 6);
    int lane = threadIdx.x & 63;
    int q   = lane & 7;
    int grp = lane >> 3;
    int bf = *flagp;
    int s = rs[node], e = rs[node + 1];
    float4 acc = make_float4(0.f, 0.f, 0.f, 0.f);
    for (int i = s + grp; i < e; i += 8) {
        int v = csr[i];
        float4 m = ts[v * 8 + q];
        acc.x += m.x; acc.y += m.y; acc.z += m.z; acc.w += m.w;
    }
#pragma unroll
    for (int off = 8; off < 64; off <<= 1) {
        acc.x += __shfl_xor(acc.x, off);
        acc.y += __shfl_xor(acc.y, off);
        acc.z += __shfl_xor(acc.z, off);
        acc.w += __shfl_xor(acc.w, off);
    }
    if (grp == 0) {
        float4 self = ts[node * 8 + q];
        float d = dis[node];
        float4 r;
        r.x = tanhf(d * (acc.x + self.x) + LD(b, q * 4 + 0, bf));
        r.y = tanhf(d * (acc.y + self.y) + LD(b, q * 4 + 1, bf));
        r.z = tanhf(d * (acc.z + self.z) + LD(b, q * 4 + 2, bf));
        r.w = tanhf(d * (acc.w + self.w) + LD(b, q * 4 + 3, bf));
        out[node * 8 + q] = r;
    }
}

// 16 lanes per node.
__global__ __launch_bounds__(256) void k_agg1(const float* __restrict__ ts4,
                                              const int* __restrict__ rs,
                                              const int* __restrict__ csr,
                                              const float* __restrict__ dis,
                                              const void* __restrict__ b4,
                                              const int* __restrict__ flagp,
                                              float* __restrict__ x4) {
    int node = blockIdx.x * 16 + (threadIdx.x >> 4);
    int lane = threadIdx.x & 15;
    int s = rs[node], e = rs[node + 1];
    float acc = 0.f;
    for (int i = s + lane; i < e; i += 16) acc += ts4[csr[i]];
#pragma unroll
    for (int off = 1; off < 16; off <<= 1) acc += __shfl_xor(acc, off);
    if (lane == 0) {
        int bf = *flagp;
        x4[node] = tanhf(dis[node] * (acc + ts4[node]) + LD(b4, 0, bf));
    }
}

// ---------- SortPooling rank ----------
__global__ __launch_bounds__(256) void k_rank(const int* __restrict__ batch,
                                              const int* __restrict__ gstart,
                                              const float* __restrict__ x4,
                                              int* __restrict__ sel) {
    int i = blockIdx.x * 256 + threadIdx.x;
    if (i >= N_NODES) return;
    int g = batch[i];
    int s = gstart[g], e = gstart[g + 1];
    float ki = x4[i];
    int rank = 0;
    for (int j = s; j < e; j++) {
        float kj = x4[j];
        rank += (kj > ki) || (kj == ki && j < i);
    }
    if (rank < KTOP) sel[g * KTOP + rank] = i;
}

// ---------- Pooled-tensor gather: one thread per element, massive TLP ----------
__global__ __launch_bounds__(256) void k_pool(const float* __restrict__ x1,
                                              const float* __restrict__ x2,
                                              const float* __restrict__ x3,
                                              const float* __restrict__ x4,
                                              const int* __restrict__ sel,
                                              float* __restrict__ P) {
    int idx = blockIdx.x * 256 + threadIdx.x;
    if (idx >= PELEM) return;
    int g = idx / (KTOP * 97);
    int r = idx - g * (KTOP * 97);
    int p = r / 97;
    int f = r - p * 97;
    int v = sel[g * KTOP + p];
    float val = 0.f;
    if (v >= 0) {
        if (f < 32)      val = x1[v * 32 + f];
        else if (f < 64) val = x2[v * 32 + f - 32];
        else if (f < 96) val = x3[v * 32 + f - 64];
        else             val = x4[v];
    }
    P[idx] = val;
}

// ---------- CNN/MLP head: coalesced P, weights staged in LDS ----------
__global__ __launch_bounds__(128) void k_head(
    const float* __restrict__ Pg,
    const void* __restrict__ w5, const void* __restrict__ b5,
    const void* __restrict__ w6, const void* __restrict__ b6,
    const void* __restrict__ f1w, const void* __restrict__ f1b,
    const void* __restrict__ f2w, const void* __restrict__ f2b,
    const int* __restrict__ flagp, void* __restrict__ out) {
    __shared__ float P[KTOP * 97];
    __shared__ float W5[16 * 97];
    __shared__ float W6[32 * 16 * 5];
    __shared__ float H5[16][30];
    __shared__ float M[16][15];
    __shared__ float H6[352];
    __shared__ float R1[128];
    __shared__ float L[10];
    __shared__ float mls;
    int g = blockIdx.x;
    int tid = threadIdx.x;
    int bf = *flagp;

    for (int i = tid; i < KTOP * 97; i += 128) P[i] = Pg[g * (KTOP * 97) + i];
    for (int i = tid; i < 16 * 97; i += 128) W5[i] = LD(w5, i, bf);
    for (int i = tid; i < 2560; i += 128) W6[i] = LD(w6, i, bf);
    __syncthreads();
    for (int idx = tid; idx < 480; idx += 128) {   // conv5 + relu
        int o = idx / 30, p = idx - o * 30;
        float acc = LD(b5, o, bf);
        const float* pr = &P[p * 97];
        const float* wr = &W5[o * 97];
        for (int f = 0; f < 97; f++) acc += wr[f] * pr[f];
        H5[o][p] = fmaxf(acc, 0.f);
    }
    __syncthreads();
    for (int idx = tid; idx < 240; idx += 128) {   // maxpool2
        int o = idx / 15, q = idx - o * 15;
        M[o][q] = fmaxf(H5[o][2 * q], H5[o][2 * q + 1]);
    }
    __syncthreads();
    for (int idx = tid; idx < 352; idx += 128) {   // conv6 + relu
        int oc = idx / 11, tp = idx - oc * 11;
        float acc = LD(b6, oc, bf);
        const float* wr = &W6[oc * 80];
        for (int ic = 0; ic < 16; ic++) {
#pragma unroll
            for (int k = 0; k < 5; k++)
                acc += wr[ic * 5 + k] * M[ic][tp + k];
        }
        H6[idx] = fmaxf(acc, 0.f);
    }
    __syncthreads();
    {   // fc1 + relu
        float acc = LD(f1b, tid, bf);
        for (int i = 0; i < 352; i++) acc += H6[i] * LD(f1w, i * 128 + tid, bf);
        R1[tid] = fmaxf(acc, 0.f);
    }
    __syncthreads();
    if (tid < 10) {   // fc2
        float acc = LD(f2b, tid, bf);
        for (int k = 0; k < 128; k++) acc += R1[k] * LD(f2w, k * 10 + tid, bf);
        L[tid] = acc;
    }
    __syncthreads();
    if (tid == 0) {
        float m = L[0];
        for (int c = 1; c < 10; c++) m = fmaxf(m, L[c]);
        float ssum = 0.f;
        for (int c = 0; c < 10; c++) ssum += expf(L[c] - m);
        mls = m + logf(ssum);
    }
    __syncthreads();
    if (tid < 10) {
        float v = L[tid] - mls;
        if (bf) ((bf16*)out)[g * 10 + tid] = __float2bfloat16(v);
        else    ((float*)out)[g * 10 + tid] = v;
    }
}

extern "C" void kernel_launch(void* const* d_in, const int* in_sizes, int n_in,
                              void* d_out, int out_size, void* d_ws, size_t ws_size,
                              hipStream_t stream) {
    const void* x   = d_in[0];
    const void* w1  = d_in[1];  const void* b1  = d_in[2];
    const void* w2  = d_in[3];  const void* b2  = d_in[4];
    const void* w3  = d_in[5];  const void* b3  = d_in[6];
    const void* w4  = d_in[7];  const void* b4  = d_in[8];
    const void* w5  = d_in[9];  const void* b5  = d_in[10];
    const void* w6  = d_in[11]; const void* b6  = d_in[12];
    const void* f1w = d_in[13]; const void* f1b = d_in[14];
    const void* f2w = d_in[15]; const void* f2b = d_in[16];
    const int* esrc  = (const int*)d_in[17];
    const int* edst  = (const int*)d_in[18];
    const int* batch = (const int*)d_in[19];

    char* w = (char*)d_ws;
    size_t off = 0;
    auto alloc = [&](size_t bytes) {
        void* p = w + off;
        off += (bytes + 255) & ~(size_t)255;
        return p;
    };
    int*   flag   = (int*)  alloc(256);
    int*   deg    = (int*)  alloc((size_t)N_NODES * 4);
    int*   rs     = (int*)  alloc((size_t)(N_NODES + 1) * 4);
    float* dis    = (float*)alloc((size_t)N_NODES * 4);
    int*   csr    = (int*)  alloc((size_t)N_EDGES * 4);
    float* t      = (float*)alloc((size_t)N_NODES * 32 * 4);
    float* x1     = (float*)alloc((size_t)N_NODES * 32 * 4);
    float* x2     = (float*)alloc((size_t)N_NODES * 32 * 4);
    float* x3     = (float*)alloc((size_t)N_NODES * 32 * 4);
    float* x4     = (float*)alloc((size_t)N_NODES * 4);
    int*   rank   = (int*)  alloc((size_t)N_EDGES * 4);
    int*   gstart = (int*)  alloc((size_t)(NGRAPH + 1) * 4);
    int*   sel    = (int*)  alloc((size_t)NGRAPH * KTOP * 4);
    float* Pg     = (float*)alloc((size_t)PELEM * 4);
    int*   bsum   = (int*)  alloc(512 * 4);
    int*   bex    = (int*)  alloc(513 * 4);
    (void)ws_size; (void)n_in; (void)in_sizes; (void)out_size;

    hipMemsetAsync(deg, 0, (size_t)N_NODES * 4, stream);
    hipMemsetAsync(sel, 0xFF, (size_t)NGRAPH * KTOP * 4, stream);

    int eb8  = (N_EDGES + 256 * EPT - 1) / (256 * EPT);
    int nb   = NB_SCAN;
    int mb32 = N_NODES / 32;
    int ab   = N_NODES / 4;
    int a1b  = N_NODES / 16;
    int pb   = (PELEM + 255) / 256;

    k_detect<<<1, 64, 0, stream>>>(w1, flag);
    k_count_rank<<<eb8, 256, 0, stream>>>(esrc, edst, deg, rank);
    k_scan1<<<nb, 256, 0, stream>>>(deg, rs, bsum);
    k_scan2<<<1, 512, 0, stream>>>(bsum, bex, nb);
    k_scan3<<<nb, 256, 0, stream>>>(rs, bex, deg, dis);
    k_gstart<<<5, 256, 0, stream>>>(batch, gstart);
    k_fill<<<eb8, 256, 0, stream>>>(esrc, edst, rank, rs, csr);

    k_mm1<<<mb32, 256, 0, stream>>>(x, w1, flag, dis, t);
    k_agg32<<<ab, 256, 0, stream>>>((const float4*)t, rs, csr, dis, b1, flag, (float4*)x1);
    k_mm32<<<mb32, 256, 0, stream>>>(x1, w2, flag, dis, t);
    k_agg32<<<ab, 256, 0, stream>>>((const float4*)t, rs, csr, dis, b2, flag, (float4*)x2);
    k_mm32<<<mb32, 256, 0, stream>>>(x2, w3, flag, dis, t);
    k_agg32<<<ab, 256, 0, stream>>>((const float4*)t, rs, csr, dis, b3, flag, (float4*)x3);
    k_mm_out1<<<(N_NODES + 7) / 8, 256, 0, stream>>>(x3, w4, flag, dis, t);
    k_agg1<<<a1b, 256, 0, stream>>>(t, rs, csr, dis, b4, flag, x4);
    k_rank<<<nb, 256, 0, stream>>>(batch, gstart, x4, sel);
    k_pool<<<pb, 256, 0, stream>>>(x1, x2, x3, x4, sel, Pg);
    k_head<<<NGRAPH, 128, 0, stream>>>(Pg, w5, b5, w6, b6,
                                       f1w, f1b, f2w, f2b, flag, (void*)d_out);
}

// Round 8
// 666.888 us; speedup vs baseline: 1.9943x; 1.1530x over previous
//
#include <hip/hip_runtime.h>
#include <hip/hip_bf16.h>

#define N_NODES 100000
#define N_EDGES 3200000
#define NGRAPH 1024
#define KTOP 30
#define PELEM (NGRAPH * KTOP * 97)         // pooled tensor elements

#define NBKT 782                            // ceil(100000 / 128) node buckets
#define NBKT_PAD 392                        // padded tile-count row (>= NTILE)
#define NTILE 391                           // edge tiles
#define TILE 8192                           // edges per tile (391*8192 >= 3.2M)

typedef __hip_bfloat16 bf16;

__device__ __forceinline__ float u2f(unsigned short h) {
    return __uint_as_float(((unsigned int)h) << 16);
}
// Flag-steered scalar load of a float-tensor input that may be bf16 or f32.
__device__ __forceinline__ float LD(const void* p, int i, int bf) {
    if (bf) return u2f(((const unsigned short*)p)[i]);
    return ((const float*)p)[i];
}

// ---------- dtype probe ----------
__global__ void k_detect(const void* w1, int* flag) {
    if (threadIdx.x == 0 && blockIdx.x == 0) {
        const unsigned short* u = (const unsigned short*)w1;
        int plausible = 0;
        for (int i = 0; i < 64; i++) {
            float a = fabsf(u2f(u[2 * i]));
            if (a == 0.f || (a >= 9.765625e-4f && a <= 2.0f)) plausible++;
        }
        *flag = (plausible >= 40) ? 1 : 0;
    }
}

// ---------- atomic-free bucket partition (digit = dst>>7) ----------
// P1: per-tile LDS histogram of dst buckets.
__global__ __launch_bounds__(256) void k_bhist(const int* __restrict__ src,
                                               const int* __restrict__ dst,
                                               int* __restrict__ bhistT) {
    __shared__ int h[NBKT];
    int blk = blockIdx.x;
    for (int i = threadIdx.x; i < NBKT; i += 256) h[i] = 0;
    __syncthreads();
    int base = blk * TILE;
    for (int i = threadIdx.x; i < TILE; i += 256) {
        int e = base + i;
        if (e < N_EDGES) {
            int s = src[e], d = dst[e];
            if (s != d) atomicAdd(&h[d >> 7], 1);
        }
    }
    __syncthreads();
    for (int i = threadIdx.x; i < NBKT; i += 256) bhistT[i * NBKT_PAD + blk] = h[i];
}

// P2a: per-bucket exclusive scan across the 391 tiles (one wave per bucket).
__global__ __launch_bounds__(64) void k_bscan(int* __restrict__ bhistT,
                                              int* __restrict__ btot) {
    int b = blockIdx.x;
    int lane = threadIdx.x;
    int* row = &bhistT[b * NBKT_PAD];
    int carry = 0;
    for (int c = 0; c < NTILE; c += 64) {
        int idx = c + lane;
        int v = (idx < NTILE) ? row[idx] : 0;
        int sc = v;
#pragma unroll
        for (int off = 1; off < 64; off <<= 1) {
            int t = __shfl_up(sc, off);
            if (lane >= off) sc += t;
        }
        if (idx < NTILE) row[idx] = sc - v + carry;   // exclusive + carry
        carry += __shfl(sc, 63);
    }
    if (lane == 0) btot[b] = carry;
}

// P2b: exclusive scan of bucket totals.
__global__ void k_btscan(const int* __restrict__ btot, int* __restrict__ bstart) {
    __shared__ int sh[1024];
    int v = ((int)threadIdx.x < NBKT) ? btot[threadIdx.x] : 0;
    sh[threadIdx.x] = v;
    __syncthreads();
    for (int off = 1; off < 1024; off <<= 1) {
        int t = (threadIdx.x >= off) ? sh[threadIdx.x - off] : 0;
        __syncthreads();
        sh[threadIdx.x] += t;
        __syncthreads();
    }
    if ((int)threadIdx.x < NBKT) bstart[threadIdx.x] = sh[threadIdx.x] - v;
    if (threadIdx.x == NBKT - 1) bstart[NBKT] = sh[threadIdx.x];
}

// P3: scatter (src,dst) pairs into bucket-grouped order; LDS cursors, no global atomics.
__global__ __launch_bounds__(256) void k_bscatter(const int* __restrict__ src,
                                                  const int* __restrict__ dst,
                                                  const int* __restrict__ bhistT,
                                                  const int* __restrict__ bstart,
                                                  int2* __restrict__ ebuf) {
    __shared__ int cur[NBKT];
    int blk = blockIdx.x;
    for (int i = threadIdx.x; i < NBKT; i += 256)
        cur[i] = bstart[i] + bhistT[i * NBKT_PAD + blk];
    __syncthreads();
    int base = blk * TILE;
    for (int i = threadIdx.x; i < TILE; i += 256) {
        int e = base + i;
        if (e < N_EDGES) {
            int s = src[e], d = dst[e];
            if (s != d) {
                int p = atomicAdd(&cur[d >> 7], 1);
                ebuf[p] = make_int2(s, d);
            }
        }
    }
}

// P4: per-bucket degree count + LDS scan -> rs/dis, then CSR fill via LDS cursors.
__global__ __launch_bounds__(256) void k_bcsr(const int2* __restrict__ ebuf,
                                              const int* __restrict__ bstart,
                                              int* __restrict__ rs,
                                              float* __restrict__ dis,
                                              int* __restrict__ csr) {
    __shared__ int dloc[128];
    __shared__ int sc[128];
    int b = blockIdx.x;
    int node0 = b << 7;
    int nn = N_NODES - node0; if (nn > 128) nn = 128;
    int tid = threadIdx.x;
    if (tid < 128) dloc[tid] = 0;
    __syncthreads();
    int s = bstart[b], e = bstart[b + 1];
    for (int i = s + tid; i < e; i += 256)
        atomicAdd(&dloc[ebuf[i].y - node0], 1);
    __syncthreads();
    if (tid < 128) sc[tid] = dloc[tid];
    __syncthreads();
    for (int off = 1; off < 128; off <<= 1) {
        int t = (tid >= off && tid < 128) ? sc[tid - off] : 0;
        __syncthreads();
        if (tid < 128) sc[tid] += t;
        __syncthreads();
    }
    // sc = inclusive scan; exclusive = sc - dloc
    if (tid < nn) {
        rs[node0 + tid] = s + sc[tid] - dloc[tid];
        dis[node0 + tid] = rsqrtf((float)dloc[tid] + 1.0f);
    }
    if (b == NBKT - 1 && tid == 0) rs[N_NODES] = e;
    __syncthreads();
    if (tid < 128) dloc[tid] = s + sc[tid] - dloc[tid];  // cursors
    __syncthreads();
    for (int i = s + tid; i < e; i += 256) {
        int2 p = ebuf[i];
        int pos = atomicAdd(&dloc[p.y - node0], 1);
        csr[pos] = p.x;
    }
}

// gstart via binary search on the (sorted) batch array.
__global__ void k_gstart(const int* __restrict__ batch, int* __restrict__ gstart) {
    int g = blockIdx.x * 256 + threadIdx.x;
    if (g > NGRAPH) return;
    int lo = 0, hi = N_NODES;
    while (lo < hi) {
        int mid = (lo + hi) >> 1;
        if (batch[mid] < g) lo = mid + 1; else hi = mid;
    }
    gstart[g] = lo;
}

// ---------- GCN layers (activations f32; ts = dis * (x @ W)) ----------
__global__ __launch_bounds__(256) void k_mm1(const void* __restrict__ x,
                                             const void* __restrict__ w,
                                             const int* __restrict__ flagp,
                                             const float* __restrict__ dis,
                                             float* __restrict__ ts) {
    __shared__ float Wl[128 * 32];
    __shared__ float Xs[32][128];
    int bf = *flagp;
    int tid = threadIdx.x;
    int nbase = blockIdx.x * 32;          // N_NODES % 32 == 0: always full
    if (bf) {
        const ushort4* wv = (const ushort4*)w;
        for (int idx = tid; idx < 1024; idx += 256) {
            ushort4 h = wv[idx];
            int p = idx * 4;
            Wl[p] = u2f(h.x); Wl[p + 1] = u2f(h.y); Wl[p + 2] = u2f(h.z); Wl[p + 3] = u2f(h.w);
        }
        const ushort4* xv = (const ushort4*)x;
        for (int idx = tid; idx < 1024; idx += 256) {
            int nd = idx >> 5, q = idx & 31;
            ushort4 h = xv[(size_t)(nbase + nd) * 32 + q];
            float* d = &Xs[nd][q * 4];
            d[0] = u2f(h.x); d[1] = u2f(h.y); d[2] = u2f(h.z); d[3] = u2f(h.w);
        }
    } else {
        const float* wf = (const float*)w;
        for (int idx = tid; idx < 4096; idx += 256) Wl[idx] = wf[idx];
        const float* xf = (const float*)x;
        for (int idx = tid; idx < 4096; idx += 256)
            Xs[idx >> 7][idx & 127] = xf[(size_t)nbase * 128 + idx];
    }
    __syncthreads();
    int grp = tid >> 5, col = tid & 31;
    for (int rep = 0; rep < 4; rep++) {
        int sub = grp + 8 * rep;
        int node = nbase + sub;
        float acc = 0.f;
#pragma unroll 8
        for (int k = 0; k < 128; k++) acc += Xs[sub][k] * Wl[k * 32 + col];
        ts[node * 32 + col] = dis[node] * acc;
    }
}

__global__ __launch_bounds__(256) void k_mm32(const float* __restrict__ xin,
                                              const void* __restrict__ w,
                                              const int* __restrict__ flagp,
                                              const float* __restrict__ dis,
                                              float* __restrict__ ts) {
    __shared__ float Wl[32 * 32];
    __shared__ float Xs[32][32];
    int bf = *flagp;
    int tid = threadIdx.x;
    int nbase = blockIdx.x * 32;
    if (bf) {
        const ushort4* wv = (const ushort4*)w;
        for (int idx = tid; idx < 256; idx += 256) {
            ushort4 h = wv[idx];
            int p = idx * 4;
            Wl[p] = u2f(h.x); Wl[p + 1] = u2f(h.y); Wl[p + 2] = u2f(h.z); Wl[p + 3] = u2f(h.w);
        }
    } else {
        const float* wf = (const float*)w;
        for (int idx = tid; idx < 1024; idx += 256) Wl[idx] = wf[idx];
    }
    {
        const float4* xv = (const float4*)xin;
        int nd = tid >> 3, q = tid & 7;
        float4 v = xv[(size_t)(nbase + nd) * 8 + q];
        float* d = &Xs[nd][q * 4];
        d[0] = v.x; d[1] = v.y; d[2] = v.z; d[3] = v.w;
    }
    __syncthreads();
    int grp = tid >> 5, col = tid & 31;
    for (int rep = 0; rep < 4; rep++) {
        int sub = grp + 8 * rep;
        int node = nbase + sub;
        float acc = 0.f;
#pragma unroll
        for (int k = 0; k < 32; k++) acc += Xs[sub][k] * Wl[k * 32 + col];
        ts[node * 32 + col] = dis[node] * acc;
    }
}

__global__ __launch_bounds__(256) void k_mm_out1(const float* __restrict__ xin,
                                                 const void* __restrict__ w4,
                                                 const int* __restrict__ flagp,
                                                 const float* __restrict__ dis,
                                                 float* __restrict__ ts4) {
    int node = blockIdx.x * 8 + (threadIdx.x >> 5);
    int lane = threadIdx.x & 31;
    if (node >= N_NODES) return;
    int bf = *flagp;
    float v = xin[node * 32 + lane] * LD(w4, lane, bf);
    for (int off = 16; off; off >>= 1) v += __shfl_down(v, off, 32);
    if (lane == 0) ts4[node] = dis[node] * v;
}

// One wave64 per node; 8 lanes per row (float4/lane) => 8 neighbor rows in
// flight per load instruction. Cross-group reduce via shfl_xor.
__global__ __launch_bounds__(256) void k_agg32(const float4* __restrict__ ts,
                                               const int* __restrict__ rs,
                                               const int* __restrict__ csr,
                                               const float* __restrict__ dis,
                                               const void* __restrict__ b,
                                               const int* __restrict__ flagp,
                                               float4* __restrict__ out) {
    int node = blockIdx.x * 4 + (threadIdx.x >> 6);
    int lane = threadIdx.x & 63;
    int q   = lane & 7;
    int grp = lane >> 3;
    int bf = *flagp;
    int s = rs[node], e = rs[node + 1];
    float4 acc = make_float4(0.f, 0.f, 0.f, 0.f);
    for (int i = s + grp; i < e; i += 8) {
        int v = csr[i];
        float4 m = ts[v * 8 + q];
        acc.x += m.x; acc.y += m.y; acc.z += m.z; acc.w += m.w;
    }
#pragma unroll
    for (int off = 8; off < 64; off <<= 1) {
        acc.x += __shfl_xor(acc.x, off);
        acc.y += __shfl_xor(acc.y, off);
        acc.z += __shfl_xor(acc.z, off);
        acc.w += __shfl_xor(acc.w, off);
    }
    if (grp == 0) {
        float4 self = ts[node * 8 + q];
        float d = dis[node];
        float4 r;
        r.x = tanhf(d * (acc.x + self.x) + LD(b, q * 4 + 0, bf));
        r.y = tanhf(d * (acc.y + self.y) + LD(b, q * 4 + 1, bf));
        r.z = tanhf(d * (acc.z + self.z) + LD(b, q * 4 + 2, bf));
        r.w = tanhf(d * (acc.w + self.w) + LD(b, q * 4 + 3, bf));
        out[node * 8 + q] = r;
    }
}

// 16 lanes per node.
__global__ __launch_bounds__(256) void k_agg1(const float* __restrict__ ts4,
                                              const int* __restrict__ rs,
                                              const int* __restrict__ csr,
                                              const float* __restrict__ dis,
                                              const void* __restrict__ b4,
                                              const int* __restrict__ flagp,
                                              float* __restrict__ x4) {
    int node = blockIdx.x * 16 + (threadIdx.x >> 4);
    int lane = threadIdx.x & 15;
    int s = rs[node], e = rs[node + 1];
    float acc = 0.f;
    for (int i = s + lane; i < e; i += 16) acc += ts4[csr[i]];
#pragma unroll
    for (int off = 1; off < 16; off <<= 1) acc += __shfl_xor(acc, off);
    if (lane == 0) {
        int bf = *flagp;
        x4[node] = tanhf(dis[node] * (acc + ts4[node]) + LD(b4, 0, bf));
    }
}

// ---------- SortPooling rank ----------
__global__ __launch_bounds__(256) void k_rank(const int* __restrict__ batch,
                                              const int* __restrict__ gstart,
                                              const float* __restrict__ x4,
                                              int* __restrict__ sel) {
    int i = blockIdx.x * 256 + threadIdx.x;
    if (i >= N_NODES) return;
    int g = batch[i];
    int s = gstart[g], e = gstart[g + 1];
    float ki = x4[i];
    int rank = 0;
    for (int j = s; j < e; j++) {
        float kj = x4[j];
        rank += (kj > ki) || (kj == ki && j < i);
    }
    if (rank < KTOP) sel[g * KTOP + rank] = i;
}

// ---------- Pooled-tensor gather ----------
__global__ __launch_bounds__(256) void k_pool(const float* __restrict__ x1,
                                              const float* __restrict__ x2,
                                              const float* __restrict__ x3,
                                              const float* __restrict__ x4,
                                              const int* __restrict__ sel,
                                              float* __restrict__ P) {
    int idx = blockIdx.x * 256 + threadIdx.x;
    if (idx >= PELEM) return;
    int g = idx / (KTOP * 97);
    int r = idx - g * (KTOP * 97);
    int p = r / 97;
    int f = r - p * 97;
    int v = sel[g * KTOP + p];
    float val = 0.f;
    if (v >= 0) {
        if (f < 32)      val = x1[v * 32 + f];
        else if (f < 64) val = x2[v * 32 + f - 32];
        else if (f < 96) val = x3[v * 32 + f - 64];
        else             val = x4[v];
    }
    P[idx] = val;
}

// ---------- CNN/MLP head: coalesced P, weights staged in LDS ----------
__global__ __launch_bounds__(128) void k_head(
    const float* __restrict__ Pg,
    const void* __restrict__ w5, const void* __restrict__ b5,
    const void* __restrict__ w6, const void* __restrict__ b6,
    const void* __restrict__ f1w, const void* __restrict__ f1b,
    const void* __restrict__ f2w, const void* __restrict__ f2b,
    const int* __restrict__ flagp, void* __restrict__ out) {
    __shared__ float P[KTOP * 97];
    __shared__ float W5[16 * 97];
    __shared__ float W6[32 * 16 * 5];
    __shared__ float H5[16][30];
    __shared__ float M[16][15];
    __shared__ float H6[352];
    __shared__ float R1[128];
    __shared__ float L[10];
    __shared__ float mls;
    int g = blockIdx.x;
    int tid = threadIdx.x;
    int bf = *flagp;

    for (int i = tid; i < KTOP * 97; i += 128) P[i] = Pg[g * (KTOP * 97) + i];
    for (int i = tid; i < 16 * 97; i += 128) W5[i] = LD(w5, i, bf);
    for (int i = tid; i < 2560; i += 128) W6[i] = LD(w6, i, bf);
    __syncthreads();
    for (int idx = tid; idx < 480; idx += 128) {   // conv5 + relu
        int o = idx / 30, p = idx - o * 30;
        float acc = LD(b5, o, bf);
        const float* pr = &P[p * 97];
        const float* wr = &W5[o * 97];
        for (int f = 0; f < 97; f++) acc += wr[f] * pr[f];
        H5[o][p] = fmaxf(acc, 0.f);
    }
    __syncthreads();
    for (int idx = tid; idx < 240; idx += 128) {   // maxpool2
        int o = idx / 15, q = idx - o * 15;
        M[o][q] = fmaxf(H5[o][2 * q], H5[o][2 * q + 1]);
    }
    __syncthreads();
    for (int idx = tid; idx < 352; idx += 128) {   // conv6 + relu
        int oc = idx / 11, tp = idx - oc * 11;
        float acc = LD(b6, oc, bf);
        const float* wr = &W6[oc * 80];
        for (int ic = 0; ic < 16; ic++) {
#pragma unroll
            for (int k = 0; k < 5; k++)
                acc += wr[ic * 5 + k] * M[ic][tp + k];
        }
        H6[idx] = fmaxf(acc, 0.f);
    }
    __syncthreads();
    {   // fc1 + relu
        float acc = LD(f1b, tid, bf);
        for (int i = 0; i < 352; i++) acc += H6[i] * LD(f1w, i * 128 + tid, bf);
        R1[tid] = fmaxf(acc, 0.f);
    }
    __syncthreads();
    if (tid < 10) {   // fc2
        float acc = LD(f2b, tid, bf);
        for (int k = 0; k < 128; k++) acc += R1[k] * LD(f2w, k * 10 + tid, bf);
        L[tid] = acc;
    }
    __syncthreads();
    if (tid == 0) {
        float m = L[0];
        for (int c = 1; c < 10; c++) m = fmaxf(m, L[c]);
        float ssum = 0.f;
        for (int c = 0; c < 10; c++) ssum += expf(L[c] - m);
        mls = m + logf(ssum);
    }
    __syncthreads();
    if (tid < 10) {
        float v = L[tid] - mls;
        if (bf) ((bf16*)out)[g * 10 + tid] = __float2bfloat16(v);
        else    ((float*)out)[g * 10 + tid] = v;
    }
}

extern "C" void kernel_launch(void* const* d_in, const int* in_sizes, int n_in,
                              void* d_out, int out_size, void* d_ws, size_t ws_size,
                              hipStream_t stream) {
    const void* x   = d_in[0];
    const void* w1  = d_in[1];  const void* b1  = d_in[2];
    const void* w2  = d_in[3];  const void* b2  = d_in[4];
    const void* w3  = d_in[5];  const void* b3  = d_in[6];
    const void* w4  = d_in[7];  const void* b4  = d_in[8];
    const void* w5  = d_in[9];  const void* b5  = d_in[10];
    const void* w6  = d_in[11]; const void* b6  = d_in[12];
    const void* f1w = d_in[13]; const void* f1b = d_in[14];
    const void* f2w = d_in[15]; const void* f2b = d_in[16];
    const int* esrc  = (const int*)d_in[17];
    const int* edst  = (const int*)d_in[18];
    const int* batch = (const int*)d_in[19];

    char* w = (char*)d_ws;
    size_t off = 0;
    auto alloc = [&](size_t bytes) {
        void* p = w + off;
        off += (bytes + 255) & ~(size_t)255;
        return p;
    };
    int*   flag   = (int*)  alloc(256);
    int*   rs     = (int*)  alloc((size_t)(N_NODES + 1) * 4);
    float* dis    = (float*)alloc((size_t)N_NODES * 4);
    int*   csr    = (int*)  alloc((size_t)N_EDGES * 4);
    float* t      = (float*)alloc((size_t)N_NODES * 32 * 4);   // aliased by ebuf (1st half)
    float* x1     = (float*)alloc((size_t)N_NODES * 32 * 4);   // aliased by ebuf (2nd half)
    float* x2     = (float*)alloc((size_t)N_NODES * 32 * 4);
    float* x3     = (float*)alloc((size_t)N_NODES * 32 * 4);
    float* x4     = (float*)alloc((size_t)N_NODES * 4);
    int*   gstart = (int*)  alloc((size_t)(NGRAPH + 1) * 4);
    int*   sel    = (int*)  alloc((size_t)NGRAPH * KTOP * 4);
    float* Pg     = (float*)alloc((size_t)PELEM * 4);
    int*   bhistT = (int*)  alloc((size_t)NBKT * NBKT_PAD * 4);
    int*   btot   = (int*)  alloc((size_t)NBKT * 4);
    int*   bstart = (int*)  alloc((size_t)(NBKT + 1) * 4);
    (void)ws_size; (void)n_in; (void)in_sizes; (void)out_size;

    // ebuf (25.6 MB of (src,dst) pairs) lives in t+x1, which are dead during preprocessing.
    int2* ebuf = (int2*)t;

    hipMemsetAsync(sel, 0xFF, (size_t)NGRAPH * KTOP * 4, stream);

    int nb   = (N_NODES + 255) / 256;
    int mb32 = N_NODES / 32;
    int ab   = N_NODES / 4;
    int a1b  = N_NODES / 16;
    int pb   = (PELEM + 255) / 256;

    k_detect<<<1, 64, 0, stream>>>(w1, flag);
    k_bhist<<<NTILE, 256, 0, stream>>>(esrc, edst, bhistT);
    k_bscan<<<NBKT, 64, 0, stream>>>(bhistT, btot);
    k_btscan<<<1, 1024, 0, stream>>>(btot, bstart);
    k_bscatter<<<NTILE, 256, 0, stream>>>(esrc, edst, bhistT, bstart, ebuf);
    k_bcsr<<<NBKT, 256, 0, stream>>>(ebuf, bstart, rs, dis, csr);
    k_gstart<<<5, 256, 0, stream>>>(batch, gstart);

    k_mm1<<<mb32, 256, 0, stream>>>(x, w1, flag, dis, t);
    k_agg32<<<ab, 256, 0, stream>>>((const float4*)t, rs, csr, dis, b1, flag, (float4*)x1);
    k_mm32<<<mb32, 256, 0, stream>>>(x1, w2, flag, dis, t);
    k_agg32<<<ab, 256, 0, stream>>>((const float4*)t, rs, csr, dis, b2, flag, (float4*)x2);
    k_mm32<<<mb32, 256, 0, stream>>>(x2, w3, flag, dis, t);
    k_agg32<<<ab, 256, 0, stream>>>((const float4*)t, rs, csr, dis, b3, flag, (float4*)x3);
    k_mm_out1<<<(N_NODES + 7) / 8, 256, 0, stream>>>(x3, w4, flag, dis, t);
    k_agg1<<<a1b, 256, 0, stream>>>(t, rs, csr, dis, b4, flag, x4);
    k_rank<<<nb, 256, 0, stream>>>(batch, gstart, x4, sel);
    k_pool<<<pb, 256, 0, stream>>>(x1, x2, x3, x4, sel, Pg);
    k_head<<<NGRAPH, 128, 0, stream>>>(Pg, w5, b5, w6, b6,
                                       f1w, f1b, f2w, f2b, flag, (void*)d_out);
}